// Round 1
// baseline (404.730 us; speedup 1.0000x reference)
//
#include <hip/hip_runtime.h>
#include <stdint.h>

// Problem constants
#define DM 512
#define NH 8
#define HDIM 64
#define TT 4096
#define PP 1024

typedef float f32x4 __attribute__((ext_vector_type(4)));
typedef __bf16 bf16x8 __attribute__((ext_vector_type(8)));
typedef unsigned short u16x8 __attribute__((ext_vector_type(8)));
typedef unsigned short u16x4 __attribute__((ext_vector_type(4)));

static __device__ __forceinline__ unsigned short f2bf(float f) {
  unsigned u = __builtin_bit_cast(unsigned, f);
  u += 0x7fff + ((u >> 16) & 1);   // RNE
  return (unsigned short)(u >> 16);
}

static __device__ __forceinline__ void load_lds16(const void* g, void* l) {
  __builtin_amdgcn_global_load_lds(
      (__attribute__((address_space(1))) void*)g,
      (__attribute__((address_space(3))) void*)l, 16, 0, 0);
}

static __device__ __forceinline__ f32x4 mfma16(bf16x8 a, bf16x8 b, f32x4 c) {
  return __builtin_amdgcn_mfma_f32_16x16x32_bf16(a, b, c, 0, 0, 0);
}

// ---------------------------------------------------------------------------
// Kernel 1: fp32 -> bf16 conversion. X's straight; W's transposed (Wt[n][k]).
// ---------------------------------------------------------------------------
__global__ __launch_bounds__(256) void k_convert(
    const float* __restrict__ tok, const float* __restrict__ pat,
    const float* __restrict__ wq, const float* __restrict__ wk,
    const float* __restrict__ wv, const float* __restrict__ wo,
    unsigned short* __restrict__ xtok, unsigned short* __restrict__ xpat,
    unsigned short* __restrict__ wt) {
  const int gid = blockIdx.x * 256 + threadIdx.x;
  const int NX = 2621440;  // (4*4096*512 + 4*1024*512) / 4
  if (gid < NX) {
    int i4 = gid * 4;
    const float* src;
    unsigned short* dst;
    int idx;
    if (i4 < 8388608) { src = tok; dst = xtok; idx = i4; }
    else              { src = pat; dst = xpat; idx = i4 - 8388608; }
    f32x4 v = *(const f32x4*)&src[idx];
    u16x4 o;
#pragma unroll
    for (int i = 0; i < 4; ++i) o[i] = f2bf(v[i]);
    *(u16x4*)&dst[idx] = o;
  } else {
    int wi = gid - NX;          // [0, 262144)
    int wid = wi >> 16;         // 0..3 -> q,k,v,o
    int e = (wi & 65535) << 2;  // element index k*512+n
    int k = e >> 9, n = e & 511;
    const float* w = (wid == 0) ? wq : (wid == 1) ? wk : (wid == 2) ? wv : wo;
    f32x4 v = *(const f32x4*)&w[e];
    unsigned short* wtb = wt + (wid << 18);
#pragma unroll
    for (int i = 0; i < 4; ++i) wtb[(n + i) * 512 + k] = f2bf(v[i]);
  }
}

// ---------------------------------------------------------------------------
// Kernel 2: bf16 GEMM  C[M x 512] = A[M x 512] @ W[512 x 512] + bias
//   Wt is W transposed: Wt[n][k].
//   mode 0/1: bf16 store row-major        (Q, K)
//   mode 2  : bf16 store transposed to VT[b][n][p]   (V)
//   mode 3  : fp32 store + residual       (out-proj)
// 128x128 tile, BK=32, 256 threads (4 waves, 2x2 of 64x64 each).
// ---------------------------------------------------------------------------
__global__ __launch_bounds__(256) void k_gemm(
    const unsigned short* __restrict__ A, const unsigned short* __restrict__ Wt,
    const float* __restrict__ bias, unsigned short* __restrict__ outb,
    float* __restrict__ outf, const float* __restrict__ resid, int mode) {
  __shared__ unsigned short sA[128 * 32];
  __shared__ unsigned short sB[128 * 32];
  const int tid = threadIdx.x;
  const int wave = tid >> 6, lane = tid & 63;
  const int q = lane >> 4, c = lane & 15;
  const int bm = blockIdx.x >> 2, bn = blockIdx.x & 3;
  const int wm = (wave >> 1) * 64, wn = (wave & 1) * 64;
  const int lr = lane >> 2, lc = (lane & 3) * 8;  // staging row/col within chunk

  f32x4 acc[4][4];
#pragma unroll
  for (int i = 0; i < 4; ++i)
#pragma unroll
    for (int j = 0; j < 4; ++j) acc[i][j] = (f32x4){0.f, 0.f, 0.f, 0.f};

  const int rowA0 = bm * 128, rowB0 = bn * 128;

  for (int k0 = 0; k0 < 512; k0 += 32) {
#pragma unroll
    for (int qq = 0; qq < 2; ++qq) {
      const int chunk = wave * 2 + qq;  // 16 rows per chunk
      load_lds16(&A[(rowA0 + chunk * 16 + lr) * 512 + k0 + lc], &sA[chunk * 512]);
      load_lds16(&Wt[(rowB0 + chunk * 16 + lr) * 512 + k0 + lc], &sB[chunk * 512]);
    }
    __syncthreads();
    bf16x8 af[4], bfr[4];
#pragma unroll
    for (int mt = 0; mt < 4; ++mt)
      af[mt] = __builtin_bit_cast(bf16x8, *(const u16x8*)&sA[(wm + mt * 16 + c) * 32 + q * 8]);
#pragma unroll
    for (int nt = 0; nt < 4; ++nt)
      bfr[nt] = __builtin_bit_cast(bf16x8, *(const u16x8*)&sB[(wn + nt * 16 + c) * 32 + q * 8]);
#pragma unroll
    for (int mt = 0; mt < 4; ++mt)
#pragma unroll
      for (int nt = 0; nt < 4; ++nt)
        acc[mt][nt] = mfma16(af[mt], bfr[nt], acc[mt][nt]);
    __syncthreads();
  }

#pragma unroll
  for (int nt = 0; nt < 4; ++nt) {
    const int col = bn * 128 + wn + nt * 16 + c;
    const float bcol = bias[col];
#pragma unroll
    for (int mt = 0; mt < 4; ++mt) {
      const int row0 = bm * 128 + wm + mt * 16 + q * 4;
#pragma unroll
      for (int r = 0; r < 4; ++r) {
        const int row = row0 + r;
        const float v = acc[mt][nt][r] + bcol;
        if (mode == 3) {
          const int o = row * 512 + col;
          outf[o] = v + resid[o];
        } else if (mode == 2) {
          outb[((row >> 10) << 19) + (col << 10) + (row & 1023)] = f2bf(v);
        } else {
          outb[row * 512 + col] = f2bf(v);
        }
      }
    }
  }
}

// ---------------------------------------------------------------------------
// Kernel 3: flash-style block-causal cross attention.
// One wave handles 16 tokens of one (b,h). Computes S^T = K.Q^T so both MFMA
// operands are contiguous 16B reads. P^T (C-layout) -> B-operand via shfl.
// ctx^T = V^T . P^T accumulated in C-layout; VT pre-transposed by k_gemm mode2.
// ---------------------------------------------------------------------------
__global__ __launch_bounds__(256) void k_attn(
    const unsigned short* __restrict__ Q,   // [B*T][512]  (h*64+hd cols)
    const unsigned short* __restrict__ K,   // [B*P][512]
    const unsigned short* __restrict__ VT,  // [B][512][1024]
    unsigned short* __restrict__ CTX) {     // [B*T][512]
  const int lane = threadIdx.x & 63;
  const int wave = threadIdx.x >> 6;
  const int q = lane >> 4, c = lane & 15;
  const int gw = blockIdx.x * 4 + wave;  // [0, 8192)
  const int it = gw & 255;
  const int h = (gw >> 8) & 7;
  const int b = gw >> 11;
  const int t0 = it * 16;
  const int t = t0 + c;

  // Q b-fragments (hoisted; k = hd)
  const int qbase = (b * TT + t) * 512 + h * 64 + q * 8;
  const bf16x8 qf0 = __builtin_bit_cast(bf16x8, *(const u16x8*)&Q[qbase]);
  const bf16x8 qf1 = __builtin_bit_cast(bf16x8, *(const u16x8*)&Q[qbase + 32]);

  f32x4 octx[4];
#pragma unroll
  for (int i = 0; i < 4; ++i) octx[i] = (f32x4){0.f, 0.f, 0.f, 0.f};
  float m_run = -1e30f, l_run = 0.f;

  const int limit = t >> 2;             // per-column max allowed patch
  const int pmax = (t0 >> 2) + 3;       // max patch for this tile
  const int ntile = (pmax >> 5) + 1;    // 32-patch tiles
  const int kbase = b * PP * 512 + h * 64 + q * 8;
  const int vbase = (b << 19) + (h * 64 + c) * 1024 + q * 8;

  for (int pt = 0; pt < ntile; ++pt) {
    const int p0 = pt * 32;
    f32x4 s0 = (f32x4){0.f, 0.f, 0.f, 0.f};
    f32x4 s1 = s0;
    {  // S^T tiles: A = K rows (m=patch), B = Q^T (n=token)
      const unsigned short* kp0 = &K[kbase + (p0 + c) * 512];
      s0 = mfma16(__builtin_bit_cast(bf16x8, *(const u16x8*)&kp0[0]), qf0, s0);
      s0 = mfma16(__builtin_bit_cast(bf16x8, *(const u16x8*)&kp0[32]), qf1, s0);
      const unsigned short* kp1 = &K[kbase + (p0 + 16 + c) * 512];
      s1 = mfma16(__builtin_bit_cast(bf16x8, *(const u16x8*)&kp1[0]), qf0, s1);
      s1 = mfma16(__builtin_bit_cast(bf16x8, *(const u16x8*)&kp1[32]), qf1, s1);
    }
    s0 *= 0.125f;  // 1/sqrt(64)
    s1 *= 0.125f;
    if (p0 + 31 > (t0 >> 2)) {  // tile touches the causal boundary
#pragma unroll
      for (int r = 0; r < 4; ++r) {
        if (p0 + q * 4 + r > limit) s0[r] = -1e30f;
        if (p0 + 16 + q * 4 + r > limit) s1[r] = -1e30f;
      }
    }
    // online softmax over patches (rows of S^T): regs + cross-quad shfl
    float tmax = fmaxf(fmaxf(fmaxf(s0[0], s0[1]), fmaxf(s0[2], s0[3])),
                       fmaxf(fmaxf(s1[0], s1[1]), fmaxf(s1[2], s1[3])));
    tmax = fmaxf(tmax, __shfl_xor(tmax, 16));
    tmax = fmaxf(tmax, __shfl_xor(tmax, 32));
    const float m_new = fmaxf(m_run, tmax);
    const float alpha = __expf(m_run - m_new);
    m_run = m_new;
    float pv0[4], pv1[4], tsum = 0.f;
#pragma unroll
    for (int r = 0; r < 4; ++r) {
      pv0[r] = __expf(s0[r] - m_new);
      pv1[r] = __expf(s1[r] - m_new);
      tsum += pv0[r] + pv1[r];
    }
    tsum += __shfl_xor(tsum, 16);
    tsum += __shfl_xor(tsum, 32);
    l_run = l_run * alpha + tsum;
#pragma unroll
    for (int mt = 0; mt < 4; ++mt) octx[mt] *= alpha;

    // P^T (C-layout) -> B-operand fragment: b[j] = P^T[q*8+j][c]
    u16x8 bp;
#pragma unroll
    for (int j = 0; j < 8; ++j) {
      const int src = (((q & 1) * 2 + (j >> 2)) << 4) | c;
      const float v0 = __shfl(pv0[j & 3], src);
      const float v1 = __shfl(pv1[j & 3], src);
      bp[j] = f2bf((q >= 2) ? v1 : v0);
    }
    const bf16x8 pb = __builtin_bit_cast(bf16x8, bp);

    // ctx^T += V^T . P^T   (A = V^T rows: m=hd, k=patch)
#pragma unroll
    for (int mt = 0; mt < 4; ++mt) {
      const bf16x8 vf =
          __builtin_bit_cast(bf16x8, *(const u16x8*)&VT[vbase + mt * 16384 + p0]);
      octx[mt] = mfma16(vf, pb, octx[mt]);
    }
  }

  const float inv = 1.f / l_run;
  const int obase = (b * TT + t) * 512 + h * 64 + q * 4;
#pragma unroll
  for (int mt = 0; mt < 4; ++mt) {
    u16x4 o;
#pragma unroll
    for (int r = 0; r < 4; ++r) o[r] = f2bf(octx[mt][r] * inv);
    *(u16x4*)&CTX[obase + mt * 16] = o;
  }
}

// ---------------------------------------------------------------------------
extern "C" void kernel_launch(void* const* d_in, const int* in_sizes, int n_in,
                              void* d_out, int out_size, void* d_ws, size_t ws_size,
                              hipStream_t stream) {
  const float* tok = (const float*)d_in[0];
  const float* pat = (const float*)d_in[1];
  const float* Wq = (const float*)d_in[2];
  const float* Wk = (const float*)d_in[3];
  const float* Wv = (const float*)d_in[4];
  const float* bq = (const float*)d_in[5];
  const float* bk = (const float*)d_in[6];
  const float* bv = (const float*)d_in[7];
  const float* Wo = (const float*)d_in[8];
  const float* bo = (const float*)d_in[9];
  float* out = (float*)d_out;

  unsigned short* ws = (unsigned short*)d_ws;
  unsigned short* XTOK = ws;               // 16 MB, reused as CTX after Q GEMM
  unsigned short* XPAT = ws + 8388608;     // 4 MB
  unsigned short* WT = ws + 10485760;      // 2 MB (Wq|Wk|Wv|Wo transposed)
  unsigned short* QB = ws + 11534336;      // 16 MB
  unsigned short* KB = ws + 19922944;      // 4 MB
  unsigned short* VTB = ws + 22020096;     // 4 MB  (total 46 MB)

  k_convert<<<11264, 256, 0, stream>>>(tok, pat, Wq, Wk, Wv, Wo, XTOK, XPAT, WT);
  k_gemm<<<512, 256, 0, stream>>>(XTOK, WT, bq, QB, nullptr, nullptr, 0);
  k_gemm<<<128, 256, 0, stream>>>(XPAT, WT + 262144, bk, KB, nullptr, nullptr, 1);
  k_gemm<<<128, 256, 0, stream>>>(XPAT, WT + 524288, bv, VTB, nullptr, nullptr, 2);
  k_attn<<<2048, 256, 0, stream>>>(QB, KB, VTB, XTOK);
  k_gemm<<<512, 256, 0, stream>>>(XTOK, WT + 786432, bo, nullptr, out, tok, 3);
}

// Round 2
// 234.374 us; speedup vs baseline: 1.7269x; 1.7269x over previous
//
#include <hip/hip_runtime.h>
#include <stdint.h>

// Problem constants
#define DM 512
#define NH 8
#define HDIM 64
#define TT 4096
#define PP 1024

typedef float f32x4 __attribute__((ext_vector_type(4)));
typedef __bf16 bf16x8 __attribute__((ext_vector_type(8)));
typedef unsigned short u16x8 __attribute__((ext_vector_type(8)));
typedef unsigned short u16x4 __attribute__((ext_vector_type(4)));

static __device__ __forceinline__ unsigned short f2bf(float f) {
  unsigned u = __builtin_bit_cast(unsigned, f);
  u += 0x7fff + ((u >> 16) & 1);   // RNE
  return (unsigned short)(u >> 16);
}

static __device__ __forceinline__ void load_lds16(const void* g, void* l) {
  __builtin_amdgcn_global_load_lds(
      (__attribute__((address_space(1))) void*)g,
      (__attribute__((address_space(3))) void*)l, 16, 0, 0);
}

static __device__ __forceinline__ f32x4 mfma16(bf16x8 a, bf16x8 b, f32x4 c) {
  return __builtin_amdgcn_mfma_f32_16x16x32_bf16(a, b, c, 0, 0, 0);
}

// ---------------------------------------------------------------------------
// Kernel 1: fp32 -> bf16 conversion. X's straight; W's transposed (Wt[n][k]).
// ---------------------------------------------------------------------------
__global__ __launch_bounds__(256) void k_convert(
    const float* __restrict__ tok, const float* __restrict__ pat,
    const float* __restrict__ wq, const float* __restrict__ wk,
    const float* __restrict__ wv, const float* __restrict__ wo,
    unsigned short* __restrict__ xtok, unsigned short* __restrict__ xpat,
    unsigned short* __restrict__ wt) {
  const int gid = blockIdx.x * 256 + threadIdx.x;
  const int NX = 2621440;  // (4*4096*512 + 4*1024*512) / 4
  if (gid < NX) {
    int i4 = gid * 4;
    const float* src;
    unsigned short* dst;
    int idx;
    if (i4 < 8388608) { src = tok; dst = xtok; idx = i4; }
    else              { src = pat; dst = xpat; idx = i4 - 8388608; }
    f32x4 v = *(const f32x4*)&src[idx];
    u16x4 o;
#pragma unroll
    for (int i = 0; i < 4; ++i) o[i] = f2bf(v[i]);
    *(u16x4*)&dst[idx] = o;
  } else {
    int wi = gid - NX;          // [0, 262144)
    int wid = wi >> 16;         // 0..3 -> q,k,v,o
    int e = (wi & 65535) << 2;  // element index k*512+n
    int k = e >> 9, n = e & 511;
    const float* w = (wid == 0) ? wq : (wid == 1) ? wk : (wid == 2) ? wv : wo;
    f32x4 v = *(const f32x4*)&w[e];
    unsigned short* wtb = wt + (wid << 18);
#pragma unroll
    for (int i = 0; i < 4; ++i) wtb[(n + i) * 512 + k] = f2bf(v[i]);
  }
}

// ---------------------------------------------------------------------------
// Kernel 2: bf16 GEMM  C[M x 512] = A[M x 512] @ W[512 x 512] + bias
//   Wt is W transposed: Wt[n][k].
//   mode 0/1: bf16 store row-major        (Q, K)
//   mode 2  : bf16 store transposed to VT[b][n][p]   (V)
//   mode 3  : fp32 store + residual       (out-proj)
// 128x128 tile, BK=32, 256 threads (4 waves, 2x2 of 64x64 each).
// ---------------------------------------------------------------------------
__device__ __forceinline__ void gemm_body(
    const unsigned short* __restrict__ A, const unsigned short* __restrict__ Wt,
    const float* __restrict__ bias, unsigned short* __restrict__ outb,
    float* __restrict__ outf, const float* __restrict__ resid, int mode,
    int bid, unsigned short* sA, unsigned short* sB) {
  const int tid = threadIdx.x;
  const int wave = tid >> 6, lane = tid & 63;
  const int q = lane >> 4, c = lane & 15;
  const int bm = bid >> 2, bn = bid & 3;
  const int wm = (wave >> 1) * 64, wn = (wave & 1) * 64;
  const int lr = lane >> 2, lc = (lane & 3) * 8;  // staging row/col within chunk

  f32x4 acc[4][4];
#pragma unroll
  for (int i = 0; i < 4; ++i)
#pragma unroll
    for (int j = 0; j < 4; ++j) acc[i][j] = (f32x4){0.f, 0.f, 0.f, 0.f};

  const int rowA0 = bm * 128, rowB0 = bn * 128;

  for (int k0 = 0; k0 < 512; k0 += 32) {
#pragma unroll
    for (int qq = 0; qq < 2; ++qq) {
      const int chunk = wave * 2 + qq;  // 16 rows per chunk
      load_lds16(&A[(rowA0 + chunk * 16 + lr) * 512 + k0 + lc], &sA[chunk * 512]);
      load_lds16(&Wt[(rowB0 + chunk * 16 + lr) * 512 + k0 + lc], &sB[chunk * 512]);
    }
    __syncthreads();
    bf16x8 af[4], bfr[4];
#pragma unroll
    for (int mt = 0; mt < 4; ++mt)
      af[mt] = __builtin_bit_cast(bf16x8, *(const u16x8*)&sA[(wm + mt * 16 + c) * 32 + q * 8]);
#pragma unroll
    for (int nt = 0; nt < 4; ++nt)
      bfr[nt] = __builtin_bit_cast(bf16x8, *(const u16x8*)&sB[(wn + nt * 16 + c) * 32 + q * 8]);
#pragma unroll
    for (int mt = 0; mt < 4; ++mt)
#pragma unroll
      for (int nt = 0; nt < 4; ++nt)
        acc[mt][nt] = mfma16(af[mt], bfr[nt], acc[mt][nt]);
    __syncthreads();
  }

#pragma unroll
  for (int nt = 0; nt < 4; ++nt) {
    const int col = bn * 128 + wn + nt * 16 + c;
    const float bcol = bias[col];
#pragma unroll
    for (int mt = 0; mt < 4; ++mt) {
      const int row0 = bm * 128 + wm + mt * 16 + q * 4;
#pragma unroll
      for (int r = 0; r < 4; ++r) {
        const int row = row0 + r;
        const float v = acc[mt][nt][r] + bcol;
        if (mode == 3) {
          const int o = row * 512 + col;
          outf[o] = v + resid[o];
        } else if (mode == 2) {
          outb[((row >> 10) << 19) + (col << 10) + (row & 1023)] = f2bf(v);
        } else {
          outb[row * 512 + col] = f2bf(v);
        }
      }
    }
  }
}

__global__ __launch_bounds__(256) void k_gemm(
    const unsigned short* __restrict__ A, const unsigned short* __restrict__ Wt,
    const float* __restrict__ bias, unsigned short* __restrict__ outb,
    float* __restrict__ outf, const float* __restrict__ resid, int mode) {
  __shared__ unsigned short sA[128 * 32];
  __shared__ unsigned short sB[128 * 32];
  gemm_body(A, Wt, bias, outb, outf, resid, mode, blockIdx.x, sA, sB);
}

// Fused K+V projection: blocks [0,128) -> K (mode 1), [128,256) -> V (mode 2)
__global__ __launch_bounds__(256) void k_gemm_kv(
    const unsigned short* __restrict__ A,
    const unsigned short* __restrict__ WtK, const unsigned short* __restrict__ WtV,
    const float* __restrict__ bk, const float* __restrict__ bv,
    unsigned short* __restrict__ KB, unsigned short* __restrict__ VTB) {
  __shared__ unsigned short sA[128 * 32];
  __shared__ unsigned short sB[128 * 32];
  const int kv = blockIdx.x >> 7;
  const int bid = blockIdx.x & 127;
  if (kv == 0)
    gemm_body(A, WtK, bk, KB, nullptr, nullptr, 1, bid, sA, sB);
  else
    gemm_body(A, WtV, bv, VTB, nullptr, nullptr, 2, bid, sA, sB);
}

// ---------------------------------------------------------------------------
// Kernel 3: flash-style block-causal cross attention, LDS-staged tiles.
// One block = one (b, h, 64-token group); 4 waves x 16 tokens.
// Per 32-patch tile the block cooperatively stages K (32x64) and V^T (64x32)
// into LDS with coalesced loads; waves read MFMA fragments via ds_read_b128
// from layouts padded for conflict-free access.
//   S^T = K.Q^T  (A = K rows from LDS, B = Q regs)
//   online softmax per patch-rows (regs) + cross-quad shfl
//   P^T (C-layout) -> B-operand via 16 shfl
//   ctx^T += V^T.P^T (A = V^T rows from LDS)
// Heavy token groups launch first (reverse tg order) for load balance.
// ---------------------------------------------------------------------------
__global__ __launch_bounds__(256) void k_attn(
    const unsigned short* __restrict__ Q,   // [B*T][512]
    const unsigned short* __restrict__ K,   // [B*P][512]
    const unsigned short* __restrict__ VT,  // [B][512][1024]
    unsigned short* __restrict__ CTX) {     // [B*T][512]
  // sK: 32 patch rows x 64 halves, row stride 80 halves (160B)
  // sV: 64 hd rows x 32 halves, row stride 40 halves (80B)
  __shared__ unsigned short sK[32 * 80];
  __shared__ unsigned short sV[64 * 40];

  const int tid = threadIdx.x;
  const int lane = tid & 63;
  const int wave = tid >> 6;
  const int q = lane >> 4, c = lane & 15;

  const int tg = 63 - (blockIdx.x >> 5);  // heavy groups first
  const int bh = blockIdx.x & 31;
  const int b = bh >> 3, h = bh & 7;
  const int t0 = tg * 64 + wave * 16;
  const int t = t0 + c;

  // Q b-fragments (hoisted)
  const int qbase = (b * TT + t) * 512 + h * 64 + q * 8;
  const bf16x8 qf0 = __builtin_bit_cast(bf16x8, *(const u16x8*)&Q[qbase]);
  const bf16x8 qf1 = __builtin_bit_cast(bf16x8, *(const u16x8*)&Q[qbase + 32]);

  f32x4 octx[4];
#pragma unroll
  for (int i = 0; i < 4; ++i) octx[i] = (f32x4){0.f, 0.f, 0.f, 0.f};
  float m_run = -1e30f, l_run = 0.f;

  const int limit = t >> 2;                     // per-token max allowed patch
  const int ntile = ((tg * 16 + 15) >> 5) + 1;  // block-level tile count

  // staging thread mapping
  const int krow = tid >> 3, kcol = (tid & 7) * 8;   // K: 32 rows x 8 chunks
  const int vrow = tid >> 2, vcol = (tid & 3) * 8;   // VT: 64 rows x 4 chunks
  const int kgbase = (b * PP + krow) * 512 + h * 64 + kcol;
  const int vgbase = (b << 19) + ((h * 64 + vrow) << 10) + vcol;

  for (int pt = 0; pt < ntile; ++pt) {
    const int p0 = pt * 32;
    // prefetch into regs (overlaps previous tile's compute)
    const u16x8 kreg = *(const u16x8*)&K[kgbase + p0 * 512];
    const u16x8 vreg = *(const u16x8*)&VT[vgbase + p0];
    __syncthreads();  // previous tile's LDS reads done
    *(u16x8*)&sK[krow * 80 + kcol] = kreg;
    *(u16x8*)&sV[vrow * 40 + vcol] = vreg;
    __syncthreads();

    f32x4 s0 = (f32x4){0.f, 0.f, 0.f, 0.f};
    f32x4 s1 = s0;
    {  // S^T tiles: A = K rows (m=patch), B = Q^T (n=token)
      const bf16x8 ka0 = __builtin_bit_cast(bf16x8, *(const u16x8*)&sK[c * 80 + q * 8]);
      const bf16x8 ka1 = __builtin_bit_cast(bf16x8, *(const u16x8*)&sK[c * 80 + 32 + q * 8]);
      const bf16x8 kb0 = __builtin_bit_cast(bf16x8, *(const u16x8*)&sK[(16 + c) * 80 + q * 8]);
      const bf16x8 kb1 = __builtin_bit_cast(bf16x8, *(const u16x8*)&sK[(16 + c) * 80 + 32 + q * 8]);
      s0 = mfma16(ka0, qf0, s0);
      s0 = mfma16(ka1, qf1, s0);
      s1 = mfma16(kb0, qf0, s1);
      s1 = mfma16(kb1, qf1, s1);
    }
    s0 *= 0.125f;  // 1/sqrt(64)
    s1 *= 0.125f;
    if (p0 + 31 > (t0 >> 2)) {  // tile touches/exceeds the causal boundary
#pragma unroll
      for (int r = 0; r < 4; ++r) {
        if (p0 + q * 4 + r > limit) s0[r] = -1e30f;
        if (p0 + 16 + q * 4 + r > limit) s1[r] = -1e30f;
      }
    }
    // online softmax over patches (rows of S^T): regs + cross-quad shfl
    float tmax = fmaxf(fmaxf(fmaxf(s0[0], s0[1]), fmaxf(s0[2], s0[3])),
                       fmaxf(fmaxf(s1[0], s1[1]), fmaxf(s1[2], s1[3])));
    tmax = fmaxf(tmax, __shfl_xor(tmax, 16));
    tmax = fmaxf(tmax, __shfl_xor(tmax, 32));
    const float m_new = fmaxf(m_run, tmax);
    const float alpha = __expf(m_run - m_new);
    m_run = m_new;
    float pv0[4], pv1[4], tsum = 0.f;
#pragma unroll
    for (int r = 0; r < 4; ++r) {
      pv0[r] = __expf(s0[r] - m_new);
      pv1[r] = __expf(s1[r] - m_new);
      tsum += pv0[r] + pv1[r];
    }
    tsum += __shfl_xor(tsum, 16);
    tsum += __shfl_xor(tsum, 32);
    l_run = l_run * alpha + tsum;
#pragma unroll
    for (int mt = 0; mt < 4; ++mt) octx[mt] *= alpha;

    // P^T (C-layout) -> B-operand fragment: b[j] = P^T[q*8+j][c]
    u16x8 bp;
#pragma unroll
    for (int j = 0; j < 8; ++j) {
      const int src = (((q & 1) * 2 + (j >> 2)) << 4) | c;
      const float v0 = __shfl(pv0[j & 3], src);
      const float v1 = __shfl(pv1[j & 3], src);
      bp[j] = f2bf((q >= 2) ? v1 : v0);
    }
    const bf16x8 pb = __builtin_bit_cast(bf16x8, bp);

    // ctx^T += V^T . P^T   (A = V^T rows from LDS: m=hd, k=patch)
#pragma unroll
    for (int mt = 0; mt < 4; ++mt) {
      const bf16x8 vf =
          __builtin_bit_cast(bf16x8, *(const u16x8*)&sV[(mt * 16 + c) * 40 + q * 8]);
      octx[mt] = mfma16(vf, pb, octx[mt]);
    }
  }

  const float inv = 1.f / l_run;
  const int obase = (b * TT + t) * 512 + h * 64 + q * 4;
#pragma unroll
  for (int mt = 0; mt < 4; ++mt) {
    u16x4 o;
#pragma unroll
    for (int r = 0; r < 4; ++r) o[r] = f2bf(octx[mt][r] * inv);
    *(u16x4*)&CTX[obase + mt * 16] = o;
  }
}

// ---------------------------------------------------------------------------
extern "C" void kernel_launch(void* const* d_in, const int* in_sizes, int n_in,
                              void* d_out, int out_size, void* d_ws, size_t ws_size,
                              hipStream_t stream) {
  const float* tok = (const float*)d_in[0];
  const float* pat = (const float*)d_in[1];
  const float* Wq = (const float*)d_in[2];
  const float* Wk = (const float*)d_in[3];
  const float* Wv = (const float*)d_in[4];
  const float* bq = (const float*)d_in[5];
  const float* bk = (const float*)d_in[6];
  const float* bv = (const float*)d_in[7];
  const float* Wo = (const float*)d_in[8];
  const float* bo = (const float*)d_in[9];
  float* out = (float*)d_out;

  unsigned short* ws = (unsigned short*)d_ws;
  unsigned short* XTOK = ws;               // 16 MB, reused as CTX after Q GEMM
  unsigned short* XPAT = ws + 8388608;     // 4 MB
  unsigned short* WT = ws + 10485760;      // 2 MB (Wq|Wk|Wv|Wo transposed)
  unsigned short* QB = ws + 11534336;      // 16 MB
  unsigned short* KB = ws + 19922944;      // 4 MB
  unsigned short* VTB = ws + 22020096;     // 4 MB  (total 46 MB)

  k_convert<<<11264, 256, 0, stream>>>(tok, pat, Wq, Wk, Wv, Wo, XTOK, XPAT, WT);
  k_gemm<<<512, 256, 0, stream>>>(XTOK, WT, bq, QB, nullptr, nullptr, 0);
  k_gemm_kv<<<256, 256, 0, stream>>>(XPAT, WT + 262144, WT + 524288, bk, bv, KB, VTB);
  k_attn<<<2048, 256, 0, stream>>>(QB, KB, VTB, XTOK);
  k_gemm<<<512, 256, 0, stream>>>(XTOK, WT + 786432, bo, nullptr, out, tok, 3);
}

// Round 3
// 227.316 us; speedup vs baseline: 1.7805x; 1.0310x over previous
//
#include <hip/hip_runtime.h>
#include <stdint.h>

// Problem constants
#define DM 512
#define NH 8
#define HDIM 64
#define TT 4096
#define PP 1024

typedef float f32x4 __attribute__((ext_vector_type(4)));
typedef __bf16 bf16x8 __attribute__((ext_vector_type(8)));
typedef unsigned short u16x8 __attribute__((ext_vector_type(8)));
typedef unsigned short u16x4 __attribute__((ext_vector_type(4)));
typedef unsigned int u32x2 __attribute__((ext_vector_type(2)));

static __device__ __forceinline__ unsigned short f2bf(float f) {
  unsigned u = __builtin_bit_cast(unsigned, f);
  u += 0x7fff + ((u >> 16) & 1);   // RNE
  return (unsigned short)(u >> 16);
}

// pack two non-negative floats to bf16 pair (round-half-up, exact enough for P in [0, e^6])
static __device__ __forceinline__ unsigned packbf(float a, float b) {
  unsigned ua = __builtin_bit_cast(unsigned, a) + 0x8000u;
  unsigned ub = __builtin_bit_cast(unsigned, b) + 0x8000u;
  return __builtin_amdgcn_perm(ub, ua, 0x07060302u);  // [a_hi16 | b_hi16]
}

static __device__ __forceinline__ void load_lds16(const void* g, void* l) {
  __builtin_amdgcn_global_load_lds(
      (__attribute__((address_space(1))) void*)g,
      (__attribute__((address_space(3))) void*)l, 16, 0, 0);
}

static __device__ __forceinline__ f32x4 mfma16(bf16x8 a, bf16x8 b, f32x4 c) {
  return __builtin_amdgcn_mfma_f32_16x16x32_bf16(a, b, c, 0, 0, 0);
}

// ---------------------------------------------------------------------------
// Kernel 1: fp32 -> bf16 conversion. X's straight; W's transposed (Wt[n][k]).
// ---------------------------------------------------------------------------
__global__ __launch_bounds__(256) void k_convert(
    const float* __restrict__ tok, const float* __restrict__ pat,
    const float* __restrict__ wq, const float* __restrict__ wk,
    const float* __restrict__ wv, const float* __restrict__ wo,
    unsigned short* __restrict__ xtok, unsigned short* __restrict__ xpat,
    unsigned short* __restrict__ wt) {
  const int gid = blockIdx.x * 256 + threadIdx.x;
  const int NX = 2621440;  // (4*4096*512 + 4*1024*512) / 4
  if (gid < NX) {
    int i4 = gid * 4;
    const float* src;
    unsigned short* dst;
    int idx;
    if (i4 < 8388608) { src = tok; dst = xtok; idx = i4; }
    else              { src = pat; dst = xpat; idx = i4 - 8388608; }
    f32x4 v = *(const f32x4*)&src[idx];
    u16x4 o;
#pragma unroll
    for (int i = 0; i < 4; ++i) o[i] = f2bf(v[i]);
    *(u16x4*)&dst[idx] = o;
  } else {
    int wi = gid - NX;          // [0, 262144)
    int wid = wi >> 16;         // 0..3 -> q,k,v,o
    int e = (wi & 65535) << 2;  // element index k*512+n
    int k = e >> 9, n = e & 511;
    const float* w = (wid == 0) ? wq : (wid == 1) ? wk : (wid == 2) ? wv : wo;
    f32x4 v = *(const f32x4*)&w[e];
    unsigned short* wtb = wt + (wid << 18);
#pragma unroll
    for (int i = 0; i < 4; ++i) wtb[(n + i) * 512 + k] = f2bf(v[i]);
  }
}

// ---------------------------------------------------------------------------
// Kernel 2: bf16 GEMM  C[M x 512] = A[M x 512] @ W[512 x 512] + bias
//   mode 0: bf16 store row-major, scaled by 0.125 (Q; folds 1/sqrt(HD))
//   mode 1: bf16 store row-major (K)
//   mode 2: bf16 store transposed to VT[b][n][p] (V)
//   mode 3: fp32 store + residual (out-proj)
// ---------------------------------------------------------------------------
__device__ __forceinline__ void gemm_body(
    const unsigned short* __restrict__ A, const unsigned short* __restrict__ Wt,
    const float* __restrict__ bias, unsigned short* __restrict__ outb,
    float* __restrict__ outf, const float* __restrict__ resid, int mode,
    int bid, unsigned short* sA, unsigned short* sB) {
  const int tid = threadIdx.x;
  const int wave = tid >> 6, lane = tid & 63;
  const int q = lane >> 4, c = lane & 15;
  const int bm = bid >> 2, bn = bid & 3;
  const int wm = (wave >> 1) * 64, wn = (wave & 1) * 64;
  const int lr = lane >> 2, lc = (lane & 3) * 8;

  f32x4 acc[4][4];
#pragma unroll
  for (int i = 0; i < 4; ++i)
#pragma unroll
    for (int j = 0; j < 4; ++j) acc[i][j] = (f32x4){0.f, 0.f, 0.f, 0.f};

  const int rowA0 = bm * 128, rowB0 = bn * 128;

  for (int k0 = 0; k0 < 512; k0 += 32) {
#pragma unroll
    for (int qq = 0; qq < 2; ++qq) {
      const int chunk = wave * 2 + qq;
      load_lds16(&A[(rowA0 + chunk * 16 + lr) * 512 + k0 + lc], &sA[chunk * 512]);
      load_lds16(&Wt[(rowB0 + chunk * 16 + lr) * 512 + k0 + lc], &sB[chunk * 512]);
    }
    __syncthreads();
    bf16x8 af[4], bfr[4];
#pragma unroll
    for (int mt = 0; mt < 4; ++mt)
      af[mt] = __builtin_bit_cast(bf16x8, *(const u16x8*)&sA[(wm + mt * 16 + c) * 32 + q * 8]);
#pragma unroll
    for (int nt = 0; nt < 4; ++nt)
      bfr[nt] = __builtin_bit_cast(bf16x8, *(const u16x8*)&sB[(wn + nt * 16 + c) * 32 + q * 8]);
#pragma unroll
    for (int mt = 0; mt < 4; ++mt)
#pragma unroll
      for (int nt = 0; nt < 4; ++nt)
        acc[mt][nt] = mfma16(af[mt], bfr[nt], acc[mt][nt]);
    __syncthreads();
  }

  const float vs = (mode == 0) ? 0.125f : 1.0f;
#pragma unroll
  for (int nt = 0; nt < 4; ++nt) {
    const int col = bn * 128 + wn + nt * 16 + c;
    const float bcol = bias[col];
#pragma unroll
    for (int mt = 0; mt < 4; ++mt) {
      const int row0 = bm * 128 + wm + mt * 16 + q * 4;
#pragma unroll
      for (int r = 0; r < 4; ++r) {
        const int row = row0 + r;
        const float v = (acc[mt][nt][r] + bcol) * vs;
        if (mode == 3) {
          const int o = row * 512 + col;
          outf[o] = v + resid[o];
        } else if (mode == 2) {
          outb[((row >> 10) << 19) + (col << 10) + (row & 1023)] = f2bf(v);
        } else {
          outb[row * 512 + col] = f2bf(v);
        }
      }
    }
  }
}

__global__ __launch_bounds__(256) void k_gemm(
    const unsigned short* __restrict__ A, const unsigned short* __restrict__ Wt,
    const float* __restrict__ bias, unsigned short* __restrict__ outb,
    float* __restrict__ outf, const float* __restrict__ resid, int mode) {
  __shared__ unsigned short sA[128 * 32];
  __shared__ unsigned short sB[128 * 32];
  gemm_body(A, Wt, bias, outb, outf, resid, mode, blockIdx.x, sA, sB);
}

__global__ __launch_bounds__(256) void k_gemm_kv(
    const unsigned short* __restrict__ A,
    const unsigned short* __restrict__ WtK, const unsigned short* __restrict__ WtV,
    const float* __restrict__ bk, const float* __restrict__ bv,
    unsigned short* __restrict__ KB, unsigned short* __restrict__ VTB) {
  __shared__ unsigned short sA[128 * 32];
  __shared__ unsigned short sB[128 * 32];
  const int kv = blockIdx.x >> 7;
  const int bid = blockIdx.x & 127;
  if (kv == 0)
    gemm_body(A, WtK, bk, KB, nullptr, nullptr, 1, bid, sA, sB);
  else
    gemm_body(A, WtV, bv, VTB, nullptr, nullptr, 2, bid, sA, sB);
}

// ---------------------------------------------------------------------------
// Kernel 3: block-causal cross attention, no-max softmax (scores ~N(0,1);
// exp is shift-invariant and overflow-safe to s~87).
// One block = one (b, h, 128-token group); 4 waves x 32 tokens (2 ttiles).
// Block = 128 tokens spans exactly 32 patches -> only the LAST tile masks.
// Per 32-patch tile: cooperative LDS stage of K (32x64) and V^T (64x32);
//   S^T = K.Q^T (2 ttiles); exp; pack via v_perm; P -> per-wave LDS [tok][patch];
//   PV B-frag = one ds_read_b128; ctx^T += V^T.P^T; l via ones-row MFMA.
// Zigzag tg order balances triangular work.
// ---------------------------------------------------------------------------
__global__ __launch_bounds__(256) void k_attn(
    const unsigned short* __restrict__ Q,   // [B*T][512], pre-scaled by 0.125
    const unsigned short* __restrict__ K,   // [B*P][512]
    const unsigned short* __restrict__ VT,  // [B][512][1024]
    unsigned short* __restrict__ CTX) {     // [B*T][512]
  __shared__ unsigned short sK[32 * 80];        // 32 patches x 64 hd, stride 80
  __shared__ unsigned short sV[64 * 40];        // 64 hd x 32 patches, stride 40
  __shared__ unsigned short sPT[4 * 32 * 40];   // per-wave P [32 tok][32 patch]

  const int tid = threadIdx.x;
  const int lane = tid & 63;
  const int wave = tid >> 6;
  const int q = lane >> 4, c = lane & 15;

  const int i = blockIdx.x >> 5;
  const int tg = (i & 1) ? (31 - (i >> 1)) : (i >> 1);  // zigzag
  const int bh = blockIdx.x & 31;
  const int b = bh >> 3, h = bh & 7;
  const int t0 = tg * 128 + wave * 32;
  const int tA = t0 + c, tB = t0 + 16 + c;

  // Q B-fragments (hoisted): B[k=hd][n=token]
  const int qbA = (b * TT + tA) * 512 + h * 64 + q * 8;
  const int qbB = (b * TT + tB) * 512 + h * 64 + q * 8;
  const bf16x8 qfA0 = __builtin_bit_cast(bf16x8, *(const u16x8*)&Q[qbA]);
  const bf16x8 qfA1 = __builtin_bit_cast(bf16x8, *(const u16x8*)&Q[qbA + 32]);
  const bf16x8 qfB0 = __builtin_bit_cast(bf16x8, *(const u16x8*)&Q[qbB]);
  const bf16x8 qfB1 = __builtin_bit_cast(bf16x8, *(const u16x8*)&Q[qbB + 32]);

  f32x4 oA[4], oB[4];
#pragma unroll
  for (int m = 0; m < 4; ++m) {
    oA[m] = (f32x4){0.f, 0.f, 0.f, 0.f};
    oB[m] = (f32x4){0.f, 0.f, 0.f, 0.f};
  }
  f32x4 lA = (f32x4){0.f, 0.f, 0.f, 0.f};
  f32x4 lB = lA;
  const u16x8 onesu = {0x3F80, 0x3F80, 0x3F80, 0x3F80, 0x3F80, 0x3F80, 0x3F80, 0x3F80};
  const bf16x8 ones = __builtin_bit_cast(bf16x8, onesu);

  const int ntile = tg + 1;
  const int krow = tid >> 3, kcol = (tid & 7) * 8;
  const int vrow = tid >> 2, vcol = (tid & 3) * 8;
  const int kg = (b * PP + krow) * 512 + h * 64 + kcol;
  const int vg = (b << 19) + ((h * 64 + vrow) << 10) + vcol;
  unsigned short* sp = &sPT[wave * 1280];

  for (int pt = 0; pt < ntile; ++pt) {
    const int p0 = pt * 32;
    const u16x8 kreg = *(const u16x8*)&K[kg + p0 * 512];
    const u16x8 vreg = *(const u16x8*)&VT[vg + p0];
    __syncthreads();
    *(u16x8*)&sK[krow * 80 + kcol] = kreg;
    *(u16x8*)&sV[vrow * 40 + vcol] = vreg;
    __syncthreads();

    const bf16x8 ka0 = __builtin_bit_cast(bf16x8, *(const u16x8*)&sK[c * 80 + q * 8]);
    const bf16x8 ka1 = __builtin_bit_cast(bf16x8, *(const u16x8*)&sK[c * 80 + 32 + q * 8]);
    const bf16x8 kb0 = __builtin_bit_cast(bf16x8, *(const u16x8*)&sK[(16 + c) * 80 + q * 8]);
    const bf16x8 kb1 = __builtin_bit_cast(bf16x8, *(const u16x8*)&sK[(16 + c) * 80 + 32 + q * 8]);

    const f32x4 z = (f32x4){0.f, 0.f, 0.f, 0.f};
    f32x4 sA0 = mfma16(ka1, qfA1, mfma16(ka0, qfA0, z));  // patches p0+q*4+r
    f32x4 sA1 = mfma16(kb1, qfA1, mfma16(kb0, qfA0, z));  // patches p0+16+q*4+r
    f32x4 sB0 = mfma16(ka1, qfB1, mfma16(ka0, qfB0, z));
    f32x4 sB1 = mfma16(kb1, qfB1, mfma16(kb0, qfB0, z));

    if (pt + 1 == ntile) {  // only the last tile crosses the causal boundary
      const int limA = tA >> 2, limB = tB >> 2;
      const int pb0 = p0 + q * 4, pb1 = p0 + 16 + q * 4;
#pragma unroll
      for (int r = 0; r < 4; ++r) {
        if (pb0 + r > limA) sA0[r] = -1e30f;
        if (pb1 + r > limA) sA1[r] = -1e30f;
        if (pb0 + r > limB) sB0[r] = -1e30f;
        if (pb1 + r > limB) sB1[r] = -1e30f;
      }
    }

    float pA0[4], pA1[4], pB0[4], pB1[4];
#pragma unroll
    for (int r = 0; r < 4; ++r) {
      pA0[r] = __expf(sA0[r]);
      pA1[r] = __expf(sA1[r]);
      pB0[r] = __expf(sB0[r]);
      pB1[r] = __expf(sB1[r]);
    }

    // P -> per-wave LDS [token][patch], stride 40 halves (80B)
    {
      u32x2 w;
      w[0] = packbf(pA0[0], pA0[1]); w[1] = packbf(pA0[2], pA0[3]);
      *(u32x2*)&sp[c * 40 + q * 4] = w;
      w[0] = packbf(pA1[0], pA1[1]); w[1] = packbf(pA1[2], pA1[3]);
      *(u32x2*)&sp[c * 40 + 16 + q * 4] = w;
      w[0] = packbf(pB0[0], pB0[1]); w[1] = packbf(pB0[2], pB0[3]);
      *(u32x2*)&sp[(16 + c) * 40 + q * 4] = w;
      w[0] = packbf(pB1[0], pB1[1]); w[1] = packbf(pB1[2], pB1[3]);
      *(u32x2*)&sp[(16 + c) * 40 + 16 + q * 4] = w;
    }
    const bf16x8 pbA = __builtin_bit_cast(bf16x8, *(const u16x8*)&sp[c * 40 + q * 8]);
    const bf16x8 pbB = __builtin_bit_cast(bf16x8, *(const u16x8*)&sp[(16 + c) * 40 + q * 8]);

    // ctx^T += V^T . P^T ; l += ones . P^T
#pragma unroll
    for (int mt = 0; mt < 4; ++mt) {
      const bf16x8 vf =
          __builtin_bit_cast(bf16x8, *(const u16x8*)&sV[(mt * 16 + c) * 40 + q * 8]);
      oA[mt] = mfma16(vf, pbA, oA[mt]);
      oB[mt] = mfma16(vf, pbB, oB[mt]);
    }
    lA = mfma16(ones, pbA, lA);
    lB = mfma16(ones, pbB, lB);
  }

  const float invA = 1.f / lA[0];
  const float invB = 1.f / lB[0];
  const int obA = (b * TT + tA) * 512 + h * 64 + q * 4;
  const int obB = (b * TT + tB) * 512 + h * 64 + q * 4;
#pragma unroll
  for (int mt = 0; mt < 4; ++mt) {
    u16x4 oa, ob;
#pragma unroll
    for (int r = 0; r < 4; ++r) {
      oa[r] = f2bf(oA[mt][r] * invA);
      ob[r] = f2bf(oB[mt][r] * invB);
    }
    *(u16x4*)&CTX[obA + mt * 16] = oa;
    *(u16x4*)&CTX[obB + mt * 16] = ob;
  }
}

// ---------------------------------------------------------------------------
extern "C" void kernel_launch(void* const* d_in, const int* in_sizes, int n_in,
                              void* d_out, int out_size, void* d_ws, size_t ws_size,
                              hipStream_t stream) {
  const float* tok = (const float*)d_in[0];
  const float* pat = (const float*)d_in[1];
  const float* Wq = (const float*)d_in[2];
  const float* Wk = (const float*)d_in[3];
  const float* Wv = (const float*)d_in[4];
  const float* bq = (const float*)d_in[5];
  const float* bk = (const float*)d_in[6];
  const float* bv = (const float*)d_in[7];
  const float* Wo = (const float*)d_in[8];
  const float* bo = (const float*)d_in[9];
  float* out = (float*)d_out;

  unsigned short* ws = (unsigned short*)d_ws;
  unsigned short* XTOK = ws;               // reused as CTX after Q GEMM
  unsigned short* XPAT = ws + 8388608;
  unsigned short* WT = ws + 10485760;      // Wq|Wk|Wv|Wo transposed
  unsigned short* QB = ws + 11534336;
  unsigned short* KB = ws + 19922944;
  unsigned short* VTB = ws + 22020096;

  k_convert<<<11264, 256, 0, stream>>>(tok, pat, Wq, Wk, Wv, Wo, XTOK, XPAT, WT);
  k_gemm<<<512, 256, 0, stream>>>(XTOK, WT, bq, QB, nullptr, nullptr, 0);
  k_gemm_kv<<<256, 256, 0, stream>>>(XPAT, WT + 262144, WT + 524288, bk, bv, KB, VTB);
  k_attn<<<1024, 256, 0, stream>>>(QB, KB, VTB, XTOK);
  k_gemm<<<512, 256, 0, stream>>>(XTOK, WT + 786432, bo, nullptr, out, tok, 3);
}

// Round 4
// 202.963 us; speedup vs baseline: 1.9941x; 1.1200x over previous
//
#include <hip/hip_runtime.h>
#include <stdint.h>

// Problem constants
#define DM 512
#define NH 8
#define HDIM 64
#define TT 4096
#define PP 1024

typedef float f32x4 __attribute__((ext_vector_type(4)));
typedef __bf16 bf16x8 __attribute__((ext_vector_type(8)));
typedef unsigned short u16x8 __attribute__((ext_vector_type(8)));
typedef unsigned short u16x4 __attribute__((ext_vector_type(4)));
typedef unsigned int u32x2 __attribute__((ext_vector_type(2)));
typedef unsigned int u32x4 __attribute__((ext_vector_type(4)));

static __device__ __forceinline__ unsigned short f2bf(float f) {
  unsigned u = __builtin_bit_cast(unsigned, f);
  u += 0x7fff + ((u >> 16) & 1);  // RNE
  return (unsigned short)(u >> 16);
}

// pack two floats -> bf16 pair (round-half-up): low u16 = bf(a), high = bf(b)
static __device__ __forceinline__ unsigned packrnd(float a, float b) {
  unsigned ua = __builtin_bit_cast(unsigned, a) + 0x8000u;
  unsigned ub = __builtin_bit_cast(unsigned, b) + 0x8000u;
  return __builtin_amdgcn_perm(ub, ua, 0x07060302u);
}
// truncating pack (for P: bias cancels in sum(Pv)/sum(P))
static __device__ __forceinline__ unsigned packtr(float a, float b) {
  return __builtin_amdgcn_perm(__builtin_bit_cast(unsigned, b),
                               __builtin_bit_cast(unsigned, a), 0x07060302u);
}

static __device__ __forceinline__ float fexp2(float x) {
#if __has_builtin(__builtin_amdgcn_exp2f)
  return __builtin_amdgcn_exp2f(x);
#else
  return __expf(x * 0.69314718055994531f);
#endif
}

static __device__ __forceinline__ void load_lds16(const void* g, void* l) {
  __builtin_amdgcn_global_load_lds(
      (__attribute__((address_space(1))) void*)g,
      (__attribute__((address_space(3))) void*)l, 16, 0, 0);
}

static __device__ __forceinline__ f32x4 mfma16(bf16x8 a, bf16x8 b, f32x4 c) {
  return __builtin_amdgcn_mfma_f32_16x16x32_bf16(a, b, c, 0, 0, 0);
}

// ---------------------------------------------------------------------------
// Weight transpose+convert: W[k][n] fp32 -> Wt[n][k] bf16, 4 matrices.
// ---------------------------------------------------------------------------
__global__ __launch_bounds__(256) void k_wconv(
    const float* __restrict__ wq, const float* __restrict__ wk,
    const float* __restrict__ wv, const float* __restrict__ wo,
    unsigned short* __restrict__ wt) {
  const int wi = blockIdx.x * 256 + threadIdx.x;  // [0, 262144)
  const int wid = wi >> 16;                       // 0..3 -> q,k,v,o
  const int e = (wi & 65535) << 2;                // element index k*512+n
  const int k = e >> 9, n = e & 511;
  const float* w = (wid == 0) ? wq : (wid == 1) ? wk : (wid == 2) ? wv : wo;
  f32x4 v = *(const f32x4*)&w[e];
  unsigned short* wtb = wt + (wid << 18);
#pragma unroll
  for (int i = 0; i < 4; ++i) wtb[(n + i) * 512 + k] = f2bf(v[i]);
}

// ---------------------------------------------------------------------------
// Projection GEMM with fused fp32->bf16 A conversion.
// C[M x 512] = A_fp32[M x 512] @ W + bias, epilogue scaled.
//   MODE 0: bf16 row-major (Q, scale folds 1/sqrt(HD) * log2(e))
//   MODE 1: bf16 row-major (K)
//   MODE 2: bf16 transposed to VT[b][n][p] (V)
// sA padded to stride 40 (conflict-free); sB via async DMA (stride 32).
// ---------------------------------------------------------------------------
template <int MODE>
__device__ __forceinline__ void gemm_fp32_body(
    const float* __restrict__ A, const unsigned short* __restrict__ Wt,
    const float* __restrict__ bias, unsigned short* __restrict__ outb,
    int bid, unsigned short* sA, unsigned short* sB, float scale) {
  const int tid = threadIdx.x;
  const int wave = tid >> 6, lane = tid & 63;
  const int q = lane >> 4, c = lane & 15;
  const int bm = bid >> 2, bn = bid & 3;
  const int wm = (wave >> 1) * 64, wn = (wave & 1) * 64;
  const int lr = lane >> 2, lc = (lane & 3) * 8;

  f32x4 acc[4][4];
#pragma unroll
  for (int i = 0; i < 4; ++i)
#pragma unroll
    for (int j = 0; j < 4; ++j) acc[i][j] = (f32x4){0.f, 0.f, 0.f, 0.f};

  const int rowA0 = bm * 128, rowB0 = bn * 128;

  for (int k0 = 0; k0 < 512; k0 += 32) {
#pragma unroll
    for (int qq = 0; qq < 2; ++qq) {
      const int chunk = wave * 2 + qq;
      const int row = chunk * 16 + lr;
      load_lds16(&Wt[(rowB0 + row) * 512 + k0 + lc], &sB[chunk * 512]);
      const f32x4 a0 = *(const f32x4*)&A[(rowA0 + row) * 512 + k0 + lc];
      const f32x4 a1 = *(const f32x4*)&A[(rowA0 + row) * 512 + k0 + lc + 4];
      u32x4 pk;
      pk[0] = packrnd(a0[0], a0[1]);
      pk[1] = packrnd(a0[2], a0[3]);
      pk[2] = packrnd(a1[0], a1[1]);
      pk[3] = packrnd(a1[2], a1[3]);
      *(u32x4*)&sA[row * 40 + lc] = pk;
    }
    __syncthreads();
    bf16x8 af[4], bfr[4];
#pragma unroll
    for (int mt = 0; mt < 4; ++mt)
      af[mt] = __builtin_bit_cast(bf16x8, *(const u16x8*)&sA[(wm + mt * 16 + c) * 40 + q * 8]);
#pragma unroll
    for (int nt = 0; nt < 4; ++nt)
      bfr[nt] = __builtin_bit_cast(bf16x8, *(const u16x8*)&sB[(wn + nt * 16 + c) * 32 + q * 8]);
#pragma unroll
    for (int mt = 0; mt < 4; ++mt)
#pragma unroll
      for (int nt = 0; nt < 4; ++nt)
        acc[mt][nt] = mfma16(af[mt], bfr[nt], acc[mt][nt]);
    __syncthreads();
  }

#pragma unroll
  for (int nt = 0; nt < 4; ++nt) {
    const int col = bn * 128 + wn + nt * 16 + c;
    const float bcol = bias[col];
#pragma unroll
    for (int mt = 0; mt < 4; ++mt) {
      const int row0 = bm * 128 + wm + mt * 16 + q * 4;
#pragma unroll
      for (int r = 0; r < 4; ++r) {
        const int row = row0 + r;
        const float v = (acc[mt][nt][r] + bcol) * scale;
        if (MODE == 2) {
          outb[((row >> 10) << 19) + (col << 10) + (row & 1023)] = f2bf(v);
        } else {
          outb[row * 512 + col] = f2bf(v);
        }
      }
    }
  }
}

__global__ __launch_bounds__(256) void k_gemm_qkv(
    const float* __restrict__ tok, const float* __restrict__ pat,
    const unsigned short* __restrict__ WT,
    const float* __restrict__ bq, const float* __restrict__ bk,
    const float* __restrict__ bv,
    unsigned short* __restrict__ QB, unsigned short* __restrict__ KB,
    unsigned short* __restrict__ VTB) {
  __shared__ unsigned short sA[128 * 40];
  __shared__ unsigned short sB[128 * 32];
  const int bid = blockIdx.x;
  if (bid < 512) {
    // scale = 0.125 * log2(e): scores come out in log2 domain for exp2
    gemm_fp32_body<0>(tok, WT, bq, QB, bid, sA, sB, 0.18033688011112042f);
  } else if (bid < 640) {
    gemm_fp32_body<1>(pat, WT + 262144, bk, KB, bid - 512, sA, sB, 1.0f);
  } else {
    gemm_fp32_body<2>(pat, WT + 524288, bv, VTB, bid - 640, sA, sB, 1.0f);
  }
}

// ---------------------------------------------------------------------------
// Out-projection GEMM (bf16 A via DMA): out = CTX @ Wo + bo + resid (fp32).
// ---------------------------------------------------------------------------
__global__ __launch_bounds__(256) void k_gemm_o(
    const unsigned short* __restrict__ A, const unsigned short* __restrict__ Wt,
    const float* __restrict__ bias, float* __restrict__ outf,
    const float* __restrict__ resid) {
  __shared__ unsigned short sA[128 * 32];
  __shared__ unsigned short sB[128 * 32];
  const int tid = threadIdx.x;
  const int wave = tid >> 6, lane = tid & 63;
  const int q = lane >> 4, c = lane & 15;
  const int bm = blockIdx.x >> 2, bn = blockIdx.x & 3;
  const int wm = (wave >> 1) * 64, wn = (wave & 1) * 64;
  const int lr = lane >> 2, lc = (lane & 3) * 8;

  f32x4 acc[4][4];
#pragma unroll
  for (int i = 0; i < 4; ++i)
#pragma unroll
    for (int j = 0; j < 4; ++j) acc[i][j] = (f32x4){0.f, 0.f, 0.f, 0.f};

  const int rowA0 = bm * 128, rowB0 = bn * 128;

  for (int k0 = 0; k0 < 512; k0 += 32) {
#pragma unroll
    for (int qq = 0; qq < 2; ++qq) {
      const int chunk = wave * 2 + qq;
      load_lds16(&A[(rowA0 + chunk * 16 + lr) * 512 + k0 + lc], &sA[chunk * 512]);
      load_lds16(&Wt[(rowB0 + chunk * 16 + lr) * 512 + k0 + lc], &sB[chunk * 512]);
    }
    __syncthreads();
    bf16x8 af[4], bfr[4];
#pragma unroll
    for (int mt = 0; mt < 4; ++mt)
      af[mt] = __builtin_bit_cast(bf16x8, *(const u16x8*)&sA[(wm + mt * 16 + c) * 32 + q * 8]);
#pragma unroll
    for (int nt = 0; nt < 4; ++nt)
      bfr[nt] = __builtin_bit_cast(bf16x8, *(const u16x8*)&sB[(wn + nt * 16 + c) * 32 + q * 8]);
#pragma unroll
    for (int mt = 0; mt < 4; ++mt)
#pragma unroll
      for (int nt = 0; nt < 4; ++nt)
        acc[mt][nt] = mfma16(af[mt], bfr[nt], acc[mt][nt]);
    __syncthreads();
  }

#pragma unroll
  for (int nt = 0; nt < 4; ++nt) {
    const int col = bn * 128 + wn + nt * 16 + c;
    const float bcol = bias[col];
#pragma unroll
    for (int mt = 0; mt < 4; ++mt) {
      const int row0 = bm * 128 + wm + mt * 16 + q * 4;
#pragma unroll
      for (int r = 0; r < 4; ++r) {
        const int row = row0 + r;
        const int o = row * 512 + col;
        outf[o] = acc[mt][nt][r] + bcol + resid[o];
      }
    }
  }
}

// ---------------------------------------------------------------------------
// Kernel 3: block-causal cross attention, no-max softmax in log2 domain
// (Q pre-scaled by 0.125*log2e; P = exp2(s); overflow-safe to s~127).
// One block = one (b, h, 128-token group); 4 waves x 32 tokens.
// Double-buffered K/V LDS staging -> one barrier per 32-patch tile.
// Conflict-free strides: sK 88, sV 40, sPT 40 (all 16B-aligned rows).
// l via ones-row MFMA; P truncation bias cancels in sum(Pv)/sum(P).
// ---------------------------------------------------------------------------
__global__ __launch_bounds__(256) void k_attn(
    const unsigned short* __restrict__ Q,   // [B*T][512], scaled
    const unsigned short* __restrict__ K,   // [B*P][512]
    const unsigned short* __restrict__ VT,  // [B][512][1024]
    unsigned short* __restrict__ CTX) {     // [B*T][512]
  __shared__ unsigned short sK[2][32 * 88];
  __shared__ unsigned short sV[2][64 * 40];
  __shared__ unsigned short sPT[4][32 * 40];

  const int tid = threadIdx.x;
  const int lane = tid & 63;
  const int wave = tid >> 6;
  const int q = lane >> 4, c = lane & 15;

  const int i = blockIdx.x >> 5;
  const int tg = (i & 1) ? (31 - (i >> 1)) : (i >> 1);  // zigzag balance
  const int bh = blockIdx.x & 31;
  const int b = bh >> 3, h = bh & 7;
  const int t0 = tg * 128 + wave * 32;
  const int tA = t0 + c, tB = t0 + 16 + c;

  const int qbA = (b * TT + tA) * 512 + h * 64 + q * 8;
  const int qbB = (b * TT + tB) * 512 + h * 64 + q * 8;
  const bf16x8 qfA0 = __builtin_bit_cast(bf16x8, *(const u16x8*)&Q[qbA]);
  const bf16x8 qfA1 = __builtin_bit_cast(bf16x8, *(const u16x8*)&Q[qbA + 32]);
  const bf16x8 qfB0 = __builtin_bit_cast(bf16x8, *(const u16x8*)&Q[qbB]);
  const bf16x8 qfB1 = __builtin_bit_cast(bf16x8, *(const u16x8*)&Q[qbB + 32]);

  f32x4 oA[4], oB[4];
#pragma unroll
  for (int m = 0; m < 4; ++m) {
    oA[m] = (f32x4){0.f, 0.f, 0.f, 0.f};
    oB[m] = (f32x4){0.f, 0.f, 0.f, 0.f};
  }
  f32x4 lA = (f32x4){0.f, 0.f, 0.f, 0.f};
  f32x4 lB = lA;
  const u16x8 onesu = {0x3F80, 0x3F80, 0x3F80, 0x3F80, 0x3F80, 0x3F80, 0x3F80, 0x3F80};
  const bf16x8 ones = __builtin_bit_cast(bf16x8, onesu);

  const int ntile = tg + 1;
  const int krow = tid >> 3, kcol = (tid & 7) * 8;
  const int vrow = tid >> 2, vcol = (tid & 3) * 8;
  const int kg = (b * PP + krow) * 512 + h * 64 + kcol;
  const int vg = (b << 19) + ((h * 64 + vrow) << 10) + vcol;
  unsigned short* sp = sPT[wave];

  // stage tile 0
  u16x8 kreg = *(const u16x8*)&K[kg];
  u16x8 vreg = *(const u16x8*)&VT[vg];
  *(u16x8*)&sK[0][krow * 88 + kcol] = kreg;
  *(u16x8*)&sV[0][vrow * 40 + vcol] = vreg;
  __syncthreads();

  for (int pt = 0; pt < ntile; ++pt) {
    const int buf = pt & 1;
    const bool more = (pt + 1 < ntile);
    if (more) {  // prefetch next tile (overlaps this tile's compute)
      kreg = *(const u16x8*)&K[kg + (pt + 1) * 32 * 512];
      vreg = *(const u16x8*)&VT[vg + (pt + 1) * 32];
    }
    const unsigned short* bK = sK[buf];
    const unsigned short* bV = sV[buf];

    const bf16x8 ka0 = __builtin_bit_cast(bf16x8, *(const u16x8*)&bK[c * 88 + q * 8]);
    const bf16x8 ka1 = __builtin_bit_cast(bf16x8, *(const u16x8*)&bK[c * 88 + 32 + q * 8]);
    const bf16x8 kb0 = __builtin_bit_cast(bf16x8, *(const u16x8*)&bK[(16 + c) * 88 + q * 8]);
    const bf16x8 kb1 = __builtin_bit_cast(bf16x8, *(const u16x8*)&bK[(16 + c) * 88 + 32 + q * 8]);

    const f32x4 z = (f32x4){0.f, 0.f, 0.f, 0.f};
    f32x4 sA0 = mfma16(ka1, qfA1, mfma16(ka0, qfA0, z));  // patches p0+q*4+r
    f32x4 sA1 = mfma16(kb1, qfA1, mfma16(kb0, qfA0, z));  // patches p0+16+q*4+r
    f32x4 sB0 = mfma16(ka1, qfB1, mfma16(ka0, qfB0, z));
    f32x4 sB1 = mfma16(kb1, qfB1, mfma16(kb0, qfB0, z));

    if (pt + 1 == ntile) {  // only the last tile crosses the causal boundary
      const int p0 = pt * 32;
      const int limA = tA >> 2, limB = tB >> 2;
      const int pb0 = p0 + q * 4, pb1 = p0 + 16 + q * 4;
#pragma unroll
      for (int r = 0; r < 4; ++r) {
        if (pb0 + r > limA) sA0[r] = -1e30f;
        if (pb1 + r > limA) sA1[r] = -1e30f;
        if (pb0 + r > limB) sB0[r] = -1e30f;
        if (pb1 + r > limB) sB1[r] = -1e30f;
      }
    }

    float pA0[4], pA1[4], pB0[4], pB1[4];
#pragma unroll
    for (int r = 0; r < 4; ++r) {
      pA0[r] = fexp2(sA0[r]);
      pA1[r] = fexp2(sA1[r]);
      pB0[r] = fexp2(sB0[r]);
      pB1[r] = fexp2(sB1[r]);
    }

    // P -> per-wave LDS [token][patch], stride 40 (truncating pack)
    {
      u32x2 w;
      w[0] = packtr(pA0[0], pA0[1]); w[1] = packtr(pA0[2], pA0[3]);
      *(u32x2*)&sp[c * 40 + q * 4] = w;
      w[0] = packtr(pA1[0], pA1[1]); w[1] = packtr(pA1[2], pA1[3]);
      *(u32x2*)&sp[c * 40 + 16 + q * 4] = w;
      w[0] = packtr(pB0[0], pB0[1]); w[1] = packtr(pB0[2], pB0[3]);
      *(u32x2*)&sp[(16 + c) * 40 + q * 4] = w;
      w[0] = packtr(pB1[0], pB1[1]); w[1] = packtr(pB1[2], pB1[3]);
      *(u32x2*)&sp[(16 + c) * 40 + 16 + q * 4] = w;
    }
    const bf16x8 pbA = __builtin_bit_cast(bf16x8, *(const u16x8*)&sp[c * 40 + q * 8]);
    const bf16x8 pbB = __builtin_bit_cast(bf16x8, *(const u16x8*)&sp[(16 + c) * 40 + q * 8]);

    // ctx^T += V^T . P^T ; l += ones . P^T
#pragma unroll
    for (int mt = 0; mt < 4; ++mt) {
      const bf16x8 vf =
          __builtin_bit_cast(bf16x8, *(const u16x8*)&bV[(mt * 16 + c) * 40 + q * 8]);
      oA[mt] = mfma16(vf, pbA, oA[mt]);
      oB[mt] = mfma16(vf, pbB, oB[mt]);
    }
    lA = mfma16(ones, pbA, lA);
    lB = mfma16(ones, pbB, lB);

    if (more) {  // write next tile into the other buffer, single barrier
      *(u16x8*)&sK[buf ^ 1][krow * 88 + kcol] = kreg;
      *(u16x8*)&sV[buf ^ 1][vrow * 40 + vcol] = vreg;
      __syncthreads();
    }
  }

  const float invA = 1.f / lA[0];
  const float invB = 1.f / lB[0];
  const int obA = (b * TT + tA) * 512 + h * 64 + q * 4;
  const int obB = (b * TT + tB) * 512 + h * 64 + q * 4;
#pragma unroll
  for (int mt = 0; mt < 4; ++mt) {
    u16x4 oa, ob;
#pragma unroll
    for (int r = 0; r < 4; ++r) {
      oa[r] = f2bf(oA[mt][r] * invA);
      ob[r] = f2bf(oB[mt][r] * invB);
    }
    *(u16x4*)&CTX[obA + mt * 16] = oa;
    *(u16x4*)&CTX[obB + mt * 16] = ob;
  }
}

// ---------------------------------------------------------------------------
extern "C" void kernel_launch(void* const* d_in, const int* in_sizes, int n_in,
                              void* d_out, int out_size, void* d_ws, size_t ws_size,
                              hipStream_t stream) {
  const float* tok = (const float*)d_in[0];
  const float* pat = (const float*)d_in[1];
  const float* Wq = (const float*)d_in[2];
  const float* Wk = (const float*)d_in[3];
  const float* Wv = (const float*)d_in[4];
  const float* bq = (const float*)d_in[5];
  const float* bk = (const float*)d_in[6];
  const float* bv = (const float*)d_in[7];
  const float* Wo = (const float*)d_in[8];
  const float* bo = (const float*)d_in[9];
  float* out = (float*)d_out;

  unsigned short* ws = (unsigned short*)d_ws;
  unsigned short* WT = ws;                  // 4 x 512 x 512
  unsigned short* QB = ws + 2097152;        // 4096*4 x 512
  unsigned short* KB = ws + 10485760;       // 1024*4 x 512
  unsigned short* VTB = ws + 12582912;      // [4][512][1024]
  unsigned short* CTX = ws + 14680064;      // 4096*4 x 512   (ends 44 MB)

  k_wconv<<<1024, 256, 0, stream>>>(Wq, Wk, Wv, Wo, WT);
  k_gemm_qkv<<<768, 256, 0, stream>>>(tok, pat, WT, bq, bk, bv, QB, KB, VTB);
  k_attn<<<1024, 256, 0, stream>>>(QB, KB, VTB, CTX);
  k_gemm_o<<<512, 256, 0, stream>>>(CTX, WT + 786432, bo, out, tok);
}

// Round 5
// 199.055 us; speedup vs baseline: 2.0333x; 1.0196x over previous
//
#include <hip/hip_runtime.h>
#include <stdint.h>

// Problem constants
#define DM 512
#define NH 8
#define HDIM 64
#define TT 4096
#define PP 1024

typedef float f32x4 __attribute__((ext_vector_type(4)));
typedef __bf16 bf16x8 __attribute__((ext_vector_type(8)));
typedef unsigned short u16x8 __attribute__((ext_vector_type(8)));
typedef unsigned short u16x4 __attribute__((ext_vector_type(4)));
typedef unsigned int u32x2 __attribute__((ext_vector_type(2)));
typedef unsigned int u32x4 __attribute__((ext_vector_type(4)));

static __device__ __forceinline__ unsigned short f2bf(float f) {
  unsigned u = __builtin_bit_cast(unsigned, f);
  u += 0x7fff + ((u >> 16) & 1);  // RNE
  return (unsigned short)(u >> 16);
}

// pack two floats -> bf16 pair (round-half-up): low u16 = bf(a), high = bf(b)
static __device__ __forceinline__ unsigned packrnd(float a, float b) {
  unsigned ua = __builtin_bit_cast(unsigned, a) + 0x8000u;
  unsigned ub = __builtin_bit_cast(unsigned, b) + 0x8000u;
  return __builtin_amdgcn_perm(ub, ua, 0x07060302u);
}
// truncating pack (for P: bias cancels in sum(Pv)/sum(P))
static __device__ __forceinline__ unsigned packtr(float a, float b) {
  return __builtin_amdgcn_perm(__builtin_bit_cast(unsigned, b),
                               __builtin_bit_cast(unsigned, a), 0x07060302u);
}

static __device__ __forceinline__ float fexp2(float x) {
#if __has_builtin(__builtin_amdgcn_exp2f)
  return __builtin_amdgcn_exp2f(x);
#else
  return __expf(x * 0.69314718055994531f);
#endif
}

static __device__ __forceinline__ void load_lds16(const void* g, void* l) {
  __builtin_amdgcn_global_load_lds(
      (__attribute__((address_space(1))) void*)g,
      (__attribute__((address_space(3))) void*)l, 16, 0, 0);
}

static __device__ __forceinline__ f32x4 mfma16(bf16x8 a, bf16x8 b, f32x4 c) {
  return __builtin_amdgcn_mfma_f32_16x16x32_bf16(a, b, c, 0, 0, 0);
}

// ---------------------------------------------------------------------------
// Weight transpose+convert: W[k][n] fp32 -> Wt[n][k] bf16, 4 matrices.
// ---------------------------------------------------------------------------
__global__ __launch_bounds__(256) void k_wconv(
    const float* __restrict__ wq, const float* __restrict__ wk,
    const float* __restrict__ wv, const float* __restrict__ wo,
    unsigned short* __restrict__ wt) {
  const int wi = blockIdx.x * 256 + threadIdx.x;  // [0, 262144)
  const int wid = wi >> 16;                       // 0..3 -> q,k,v,o
  const int e = (wi & 65535) << 2;                // element index k*512+n
  const int k = e >> 9, n = e & 511;
  const float* w = (wid == 0) ? wq : (wid == 1) ? wk : (wid == 2) ? wv : wo;
  f32x4 v = *(const f32x4*)&w[e];
  unsigned short* wtb = wt + (wid << 18);
#pragma unroll
  for (int i = 0; i < 4; ++i) wtb[(n + i) * 512 + k] = f2bf(v[i]);
}

// ---------------------------------------------------------------------------
// Projection GEMM with fused fp32->bf16 A conversion.
//   MODE 0: bf16 row-major (Q, scale folds 1/sqrt(HD) * log2(e))
//   MODE 1: bf16 row-major (K)
//   MODE 2: bf16 transposed to VT[b][n][p] (V)
// ---------------------------------------------------------------------------
template <int MODE>
__device__ __forceinline__ void gemm_fp32_body(
    const float* __restrict__ A, const unsigned short* __restrict__ Wt,
    const float* __restrict__ bias, unsigned short* __restrict__ outb,
    int bid, unsigned short* sA, unsigned short* sB, float scale) {
  const int tid = threadIdx.x;
  const int wave = tid >> 6, lane = tid & 63;
  const int q = lane >> 4, c = lane & 15;
  const int bm = bid >> 2, bn = bid & 3;
  const int wm = (wave >> 1) * 64, wn = (wave & 1) * 64;
  const int lr = lane >> 2, lc = (lane & 3) * 8;

  f32x4 acc[4][4];
#pragma unroll
  for (int i = 0; i < 4; ++i)
#pragma unroll
    for (int j = 0; j < 4; ++j) acc[i][j] = (f32x4){0.f, 0.f, 0.f, 0.f};

  const int rowA0 = bm * 128, rowB0 = bn * 128;

  for (int k0 = 0; k0 < 512; k0 += 32) {
#pragma unroll
    for (int qq = 0; qq < 2; ++qq) {
      const int chunk = wave * 2 + qq;
      const int row = chunk * 16 + lr;
      load_lds16(&Wt[(rowB0 + row) * 512 + k0 + lc], &sB[chunk * 512]);
      const f32x4 a0 = *(const f32x4*)&A[(rowA0 + row) * 512 + k0 + lc];
      const f32x4 a1 = *(const f32x4*)&A[(rowA0 + row) * 512 + k0 + lc + 4];
      u32x4 pk;
      pk[0] = packrnd(a0[0], a0[1]);
      pk[1] = packrnd(a0[2], a0[3]);
      pk[2] = packrnd(a1[0], a1[1]);
      pk[3] = packrnd(a1[2], a1[3]);
      *(u32x4*)&sA[row * 40 + lc] = pk;
    }
    __syncthreads();
    bf16x8 af[4], bfr[4];
#pragma unroll
    for (int mt = 0; mt < 4; ++mt)
      af[mt] = __builtin_bit_cast(bf16x8, *(const u16x8*)&sA[(wm + mt * 16 + c) * 40 + q * 8]);
#pragma unroll
    for (int nt = 0; nt < 4; ++nt)
      bfr[nt] = __builtin_bit_cast(bf16x8, *(const u16x8*)&sB[(wn + nt * 16 + c) * 32 + q * 8]);
#pragma unroll
    for (int mt = 0; mt < 4; ++mt)
#pragma unroll
      for (int nt = 0; nt < 4; ++nt)
        acc[mt][nt] = mfma16(af[mt], bfr[nt], acc[mt][nt]);
    __syncthreads();
  }

#pragma unroll
  for (int nt = 0; nt < 4; ++nt) {
    const int col = bn * 128 + wn + nt * 16 + c;
    const float bcol = bias[col];
#pragma unroll
    for (int mt = 0; mt < 4; ++mt) {
      const int row0 = bm * 128 + wm + mt * 16 + q * 4;
#pragma unroll
      for (int r = 0; r < 4; ++r) {
        const int row = row0 + r;
        const float v = (acc[mt][nt][r] + bcol) * scale;
        if (MODE == 2) {
          outb[((row >> 10) << 19) + (col << 10) + (row & 1023)] = f2bf(v);
        } else {
          outb[row * 512 + col] = f2bf(v);
        }
      }
    }
  }
}

__global__ __launch_bounds__(256) void k_gemm_qkv(
    const float* __restrict__ tok, const float* __restrict__ pat,
    const unsigned short* __restrict__ WT,
    const float* __restrict__ bq, const float* __restrict__ bk,
    const float* __restrict__ bv,
    unsigned short* __restrict__ QB, unsigned short* __restrict__ KB,
    unsigned short* __restrict__ VTB) {
  __shared__ unsigned short sA[128 * 40];
  __shared__ unsigned short sB[128 * 32];
  const int bid = blockIdx.x;
  if (bid < 512) {
    // scale = 0.125 * log2(e): scores come out in log2 domain for exp2
    gemm_fp32_body<0>(tok, WT, bq, QB, bid, sA, sB, 0.18033688011112042f);
  } else if (bid < 640) {
    gemm_fp32_body<1>(pat, WT + 262144, bk, KB, bid - 512, sA, sB, 1.0f);
  } else {
    gemm_fp32_body<2>(pat, WT + 524288, bv, VTB, bid - 640, sA, sB, 1.0f);
  }
}

// ---------------------------------------------------------------------------
// Out-projection GEMM (bf16 A via DMA): out = CTX @ Wo + bo + resid (fp32).
// ---------------------------------------------------------------------------
__global__ __launch_bounds__(256) void k_gemm_o(
    const unsigned short* __restrict__ A, const unsigned short* __restrict__ Wt,
    const float* __restrict__ bias, float* __restrict__ outf,
    const float* __restrict__ resid) {
  __shared__ unsigned short sA[128 * 32];
  __shared__ unsigned short sB[128 * 32];
  const int tid = threadIdx.x;
  const int wave = tid >> 6, lane = tid & 63;
  const int q = lane >> 4, c = lane & 15;
  const int bm = blockIdx.x >> 2, bn = blockIdx.x & 3;
  const int wm = (wave >> 1) * 64, wn = (wave & 1) * 64;
  const int lr = lane >> 2, lc = (lane & 3) * 8;

  f32x4 acc[4][4];
#pragma unroll
  for (int i = 0; i < 4; ++i)
#pragma unroll
    for (int j = 0; j < 4; ++j) acc[i][j] = (f32x4){0.f, 0.f, 0.f, 0.f};

  const int rowA0 = bm * 128, rowB0 = bn * 128;

  for (int k0 = 0; k0 < 512; k0 += 32) {
#pragma unroll
    for (int qq = 0; qq < 2; ++qq) {
      const int chunk = wave * 2 + qq;
      load_lds16(&A[(rowA0 + chunk * 16 + lr) * 512 + k0 + lc], &sA[chunk * 512]);
      load_lds16(&Wt[(rowB0 + chunk * 16 + lr) * 512 + k0 + lc], &sB[chunk * 512]);
    }
    __syncthreads();
    bf16x8 af[4], bfr[4];
#pragma unroll
    for (int mt = 0; mt < 4; ++mt)
      af[mt] = __builtin_bit_cast(bf16x8, *(const u16x8*)&sA[(wm + mt * 16 + c) * 32 + q * 8]);
#pragma unroll
    for (int nt = 0; nt < 4; ++nt)
      bfr[nt] = __builtin_bit_cast(bf16x8, *(const u16x8*)&sB[(wn + nt * 16 + c) * 32 + q * 8]);
#pragma unroll
    for (int mt = 0; mt < 4; ++mt)
#pragma unroll
      for (int nt = 0; nt < 4; ++nt)
        acc[mt][nt] = mfma16(af[mt], bfr[nt], acc[mt][nt]);
    __syncthreads();
  }

#pragma unroll
  for (int nt = 0; nt < 4; ++nt) {
    const int col = bn * 128 + wn + nt * 16 + c;
    const float bcol = bias[col];
#pragma unroll
    for (int mt = 0; mt < 4; ++mt) {
      const int row0 = bm * 128 + wm + mt * 16 + q * 4;
#pragma unroll
      for (int r = 0; r < 4; ++r) {
        const int row = row0 + r;
        const int o = row * 512 + col;
        outf[o] = acc[mt][nt][r] + bcol + resid[o];
      }
    }
  }
}

// ---------------------------------------------------------------------------
// Kernel 3: block-causal cross attention, no-max softmax in log2 domain.
// 512 blocks, each = (b, h) x token-group PAIR (p, 31-p) processed
// sequentially -> every block does exactly (p+1)+(32-p) = 33 tiles.
// Per-CU work is uniform (66 tiles) under ANY 2-blocks/CU assignment —
// no dispatch-order assumption (round-4 zigzag gave 28..92 tiles/CU).
// ---------------------------------------------------------------------------
__global__ __launch_bounds__(256) void k_attn(
    const unsigned short* __restrict__ Q,   // [B*T][512], scaled by .125*log2e
    const unsigned short* __restrict__ K,   // [B*P][512]
    const unsigned short* __restrict__ VT,  // [B][512][1024]
    unsigned short* __restrict__ CTX) {     // [B*T][512]
  __shared__ unsigned short sK[2][32 * 88];
  __shared__ unsigned short sV[2][64 * 40];
  __shared__ unsigned short sPT[4][32 * 40];

  const int tid = threadIdx.x;
  const int lane = tid & 63;
  const int wave = tid >> 6;
  const int q = lane >> 4, c = lane & 15;

  const int p = blockIdx.x >> 5;          // [0,16): pair index
  const int bh = blockIdx.x & 31;
  const int b = bh >> 3, h = bh & 7;

  const u16x8 onesu = {0x3F80, 0x3F80, 0x3F80, 0x3F80, 0x3F80, 0x3F80, 0x3F80, 0x3F80};
  const bf16x8 ones = __builtin_bit_cast(bf16x8, onesu);

  const int krow = tid >> 3, kcol = (tid & 7) * 8;
  const int vrow = tid >> 2, vcol = (tid & 3) * 8;
  const int kg = (b * PP + krow) * 512 + h * 64 + kcol;
  const int vg = (b << 19) + ((h * 64 + vrow) << 10) + vcol;
  unsigned short* sp = sPT[wave];

#pragma unroll 1
  for (int phase = 0; phase < 2; ++phase) {
    const int tg = phase ? (31 - p) : p;
    const int t0 = tg * 128 + wave * 32;
    const int tA = t0 + c, tB = t0 + 16 + c;

    const int qbA = (b * TT + tA) * 512 + h * 64 + q * 8;
    const int qbB = (b * TT + tB) * 512 + h * 64 + q * 8;
    const bf16x8 qfA0 = __builtin_bit_cast(bf16x8, *(const u16x8*)&Q[qbA]);
    const bf16x8 qfA1 = __builtin_bit_cast(bf16x8, *(const u16x8*)&Q[qbA + 32]);
    const bf16x8 qfB0 = __builtin_bit_cast(bf16x8, *(const u16x8*)&Q[qbB]);
    const bf16x8 qfB1 = __builtin_bit_cast(bf16x8, *(const u16x8*)&Q[qbB + 32]);

    f32x4 oA[4], oB[4];
#pragma unroll
    for (int m = 0; m < 4; ++m) {
      oA[m] = (f32x4){0.f, 0.f, 0.f, 0.f};
      oB[m] = (f32x4){0.f, 0.f, 0.f, 0.f};
    }
    f32x4 lA = (f32x4){0.f, 0.f, 0.f, 0.f};
    f32x4 lB = lA;

    const int ntile = tg + 1;

    // guard the double-buffer against the previous phase's in-flight reads
    __syncthreads();
    u16x8 kreg = *(const u16x8*)&K[kg];
    u16x8 vreg = *(const u16x8*)&VT[vg];
    *(u16x8*)&sK[0][krow * 88 + kcol] = kreg;
    *(u16x8*)&sV[0][vrow * 40 + vcol] = vreg;
    __syncthreads();

#pragma unroll 1
    for (int pt = 0; pt < ntile; ++pt) {
      const int buf = pt & 1;
      const bool more = (pt + 1 < ntile);
      if (more) {  // prefetch next tile (overlaps this tile's compute)
        kreg = *(const u16x8*)&K[kg + (pt + 1) * 32 * 512];
        vreg = *(const u16x8*)&VT[vg + (pt + 1) * 32];
      }
      const unsigned short* bK = sK[buf];
      const unsigned short* bV = sV[buf];

      const bf16x8 ka0 = __builtin_bit_cast(bf16x8, *(const u16x8*)&bK[c * 88 + q * 8]);
      const bf16x8 ka1 = __builtin_bit_cast(bf16x8, *(const u16x8*)&bK[c * 88 + 32 + q * 8]);
      const bf16x8 kb0 = __builtin_bit_cast(bf16x8, *(const u16x8*)&bK[(16 + c) * 88 + q * 8]);
      const bf16x8 kb1 = __builtin_bit_cast(bf16x8, *(const u16x8*)&bK[(16 + c) * 88 + 32 + q * 8]);

      const f32x4 z = (f32x4){0.f, 0.f, 0.f, 0.f};
      f32x4 sA0 = mfma16(ka1, qfA1, mfma16(ka0, qfA0, z));  // patches p0+q*4+r
      f32x4 sA1 = mfma16(kb1, qfA1, mfma16(kb0, qfA0, z));  // patches p0+16+q*4+r
      f32x4 sB0 = mfma16(ka1, qfB1, mfma16(ka0, qfB0, z));
      f32x4 sB1 = mfma16(kb1, qfB1, mfma16(kb0, qfB0, z));

      if (pt + 1 == ntile) {  // only the last tile crosses the causal boundary
        const int p0 = pt * 32;
        const int limA = tA >> 2, limB = tB >> 2;
        const int pb0 = p0 + q * 4, pb1 = p0 + 16 + q * 4;
#pragma unroll
        for (int r = 0; r < 4; ++r) {
          if (pb0 + r > limA) sA0[r] = -1e30f;
          if (pb1 + r > limA) sA1[r] = -1e30f;
          if (pb0 + r > limB) sB0[r] = -1e30f;
          if (pb1 + r > limB) sB1[r] = -1e30f;
        }
      }

      float pA0[4], pA1[4], pB0[4], pB1[4];
#pragma unroll
      for (int r = 0; r < 4; ++r) {
        pA0[r] = fexp2(sA0[r]);
        pA1[r] = fexp2(sA1[r]);
        pB0[r] = fexp2(sB0[r]);
        pB1[r] = fexp2(sB1[r]);
      }

      // P -> per-wave LDS [token][patch], stride 40 (truncating pack)
      {
        u32x2 w;
        w[0] = packtr(pA0[0], pA0[1]); w[1] = packtr(pA0[2], pA0[3]);
        *(u32x2*)&sp[c * 40 + q * 4] = w;
        w[0] = packtr(pA1[0], pA1[1]); w[1] = packtr(pA1[2], pA1[3]);
        *(u32x2*)&sp[c * 40 + 16 + q * 4] = w;
        w[0] = packtr(pB0[0], pB0[1]); w[1] = packtr(pB0[2], pB0[3]);
        *(u32x2*)&sp[(16 + c) * 40 + q * 4] = w;
        w[0] = packtr(pB1[0], pB1[1]); w[1] = packtr(pB1[2], pB1[3]);
        *(u32x2*)&sp[(16 + c) * 40 + 16 + q * 4] = w;
      }
      const bf16x8 pbA = __builtin_bit_cast(bf16x8, *(const u16x8*)&sp[c * 40 + q * 8]);
      const bf16x8 pbB = __builtin_bit_cast(bf16x8, *(const u16x8*)&sp[(16 + c) * 40 + q * 8]);

      // ctx^T += V^T . P^T ; l += ones . P^T
#pragma unroll
      for (int mt = 0; mt < 4; ++mt) {
        const bf16x8 vf =
            __builtin_bit_cast(bf16x8, *(const u16x8*)&bV[(mt * 16 + c) * 40 + q * 8]);
        oA[mt] = mfma16(vf, pbA, oA[mt]);
        oB[mt] = mfma16(vf, pbB, oB[mt]);
      }
      lA = mfma16(ones, pbA, lA);
      lB = mfma16(ones, pbB, lB);

      if (more) {  // write next tile into the other buffer, single barrier
        *(u16x8*)&sK[buf ^ 1][krow * 88 + kcol] = kreg;
        *(u16x8*)&sV[buf ^ 1][vrow * 40 + vcol] = vreg;
        __syncthreads();
      }
    }

    const float invA = 1.f / lA[0];
    const float invB = 1.f / lB[0];
    const int obA = (b * TT + tA) * 512 + h * 64 + q * 4;
    const int obB = (b * TT + tB) * 512 + h * 64 + q * 4;
#pragma unroll
    for (int mt = 0; mt < 4; ++mt) {
      u16x4 oa, ob;
#pragma unroll
      for (int r = 0; r < 4; ++r) {
        oa[r] = f2bf(oA[mt][r] * invA);
        ob[r] = f2bf(oB[mt][r] * invB);
      }
      *(u16x4*)&CTX[obA + mt * 16] = oa;
      *(u16x4*)&CTX[obB + mt * 16] = ob;
    }
  }
}

// ---------------------------------------------------------------------------
extern "C" void kernel_launch(void* const* d_in, const int* in_sizes, int n_in,
                              void* d_out, int out_size, void* d_ws, size_t ws_size,
                              hipStream_t stream) {
  const float* tok = (const float*)d_in[0];
  const float* pat = (const float*)d_in[1];
  const float* Wq = (const float*)d_in[2];
  const float* Wk = (const float*)d_in[3];
  const float* Wv = (const float*)d_in[4];
  const float* bq = (const float*)d_in[5];
  const float* bk = (const float*)d_in[6];
  const float* bv = (const float*)d_in[7];
  const float* Wo = (const float*)d_in[8];
  const float* bo = (const float*)d_in[9];
  float* out = (float*)d_out;

  unsigned short* ws = (unsigned short*)d_ws;
  unsigned short* WT = ws;                  // 4 x 512 x 512
  unsigned short* QB = ws + 2097152;        // 4096*4 x 512
  unsigned short* KB = ws + 10485760;       // 1024*4 x 512
  unsigned short* VTB = ws + 12582912;      // [4][512][1024]
  unsigned short* CTX = ws + 14680064;      // 4096*4 x 512   (ends 44 MB)

  k_wconv<<<1024, 256, 0, stream>>>(Wq, Wk, Wv, Wo, WT);
  k_gemm_qkv<<<768, 256, 0, stream>>>(tok, pat, WT, bq, bk, bv, QB, KB, VTB);
  k_attn<<<512, 256, 0, stream>>>(QB, KB, VTB, CTX);
  k_gemm_o<<<512, 256, 0, stream>>>(CTX, WT + 786432, bo, out, tok);
}

// Round 7
// 196.633 us; speedup vs baseline: 2.0583x; 1.0123x over previous
//
#include <hip/hip_runtime.h>
#include <stdint.h>

// Problem constants
#define DM 512
#define NH 8
#define HDIM 64
#define TT 4096
#define PP 1024

typedef float f32x4 __attribute__((ext_vector_type(4)));
typedef __bf16 bf16x8 __attribute__((ext_vector_type(8)));
typedef unsigned short u16x8 __attribute__((ext_vector_type(8)));
typedef unsigned short u16x4 __attribute__((ext_vector_type(4)));
typedef unsigned int u32x2 __attribute__((ext_vector_type(2)));
typedef unsigned int u32x4 __attribute__((ext_vector_type(4)));

static __device__ __forceinline__ unsigned short f2bf(float f) {
  unsigned u = __builtin_bit_cast(unsigned, f);
  u += 0x7fff + ((u >> 16) & 1);  // RNE
  return (unsigned short)(u >> 16);
}

// pack two floats -> bf16 pair (round-half-up): low u16 = bf(a), high = bf(b)
static __device__ __forceinline__ unsigned packrnd(float a, float b) {
  unsigned ua = __builtin_bit_cast(unsigned, a) + 0x8000u;
  unsigned ub = __builtin_bit_cast(unsigned, b) + 0x8000u;
  return __builtin_amdgcn_perm(ub, ua, 0x07060302u);
}
// truncating pack (for P: bias cancels in sum(Pv)/sum(P))
static __device__ __forceinline__ unsigned packtr(float a, float b) {
  return __builtin_amdgcn_perm(__builtin_bit_cast(unsigned, b),
                               __builtin_bit_cast(unsigned, a), 0x07060302u);
}

static __device__ __forceinline__ float fexp2(float x) {
#if __has_builtin(__builtin_amdgcn_exp2f)
  return __builtin_amdgcn_exp2f(x);
#else
  return __expf(x * 0.69314718055994531f);
#endif
}

static __device__ __forceinline__ void load_lds16(const void* g, void* l) {
  __builtin_amdgcn_global_load_lds(
      (__attribute__((address_space(1))) void*)g,
      (__attribute__((address_space(3))) void*)l, 16, 0, 0);
}

static __device__ __forceinline__ f32x4 mfma16(bf16x8 a, bf16x8 b, f32x4 c) {
  return __builtin_amdgcn_mfma_f32_16x16x32_bf16(a, b, c, 0, 0, 0);
}

// ---------------------------------------------------------------------------
// Weight transpose+convert: W[k][n] fp32 -> Wt[n][k] bf16, 4 matrices.
// ---------------------------------------------------------------------------
__global__ __launch_bounds__(256) void k_wconv(
    const float* __restrict__ wq, const float* __restrict__ wk,
    const float* __restrict__ wv, const float* __restrict__ wo,
    unsigned short* __restrict__ wt) {
  const int wi = blockIdx.x * 256 + threadIdx.x;  // [0, 262144)
  const int wid = wi >> 16;                       // 0..3 -> q,k,v,o
  const int e = (wi & 65535) << 2;                // element index k*512+n
  const int k = e >> 9, n = e & 511;
  const float* w = (wid == 0) ? wq : (wid == 1) ? wk : (wid == 2) ? wv : wo;
  f32x4 v = *(const f32x4*)&w[e];
  unsigned short* wtb = wt + (wid << 18);
#pragma unroll
  for (int i = 0; i < 4; ++i) wtb[(n + i) * 512 + k] = f2bf(v[i]);
}

// ---------------------------------------------------------------------------
// Projection GEMM with fused fp32->bf16 A conversion.
//   MODE 0: bf16 row-major (Q, scale folds 1/sqrt(HD) * log2(e))
//   MODE 1: bf16 row-major (K)
//   MODE 2: bf16 transposed to VT[b][n][p] (V)
// ---------------------------------------------------------------------------
template <int MODE>
__device__ __forceinline__ void gemm_fp32_body(
    const float* __restrict__ A, const unsigned short* __restrict__ Wt,
    const float* __restrict__ bias, unsigned short* __restrict__ outb,
    int bid, unsigned short* sA, unsigned short* sB, float scale) {
  const int tid = threadIdx.x;
  const int wave = tid >> 6, lane = tid & 63;
  const int q = lane >> 4, c = lane & 15;
  const int bm = bid >> 2, bn = bid & 3;
  const int wm = (wave >> 1) * 64, wn = (wave & 1) * 64;
  const int lr = lane >> 2, lc = (lane & 3) * 8;

  f32x4 acc[4][4];
#pragma unroll
  for (int i = 0; i < 4; ++i)
#pragma unroll
    for (int j = 0; j < 4; ++j) acc[i][j] = (f32x4){0.f, 0.f, 0.f, 0.f};

  const int rowA0 = bm * 128, rowB0 = bn * 128;

  for (int k0 = 0; k0 < 512; k0 += 32) {
#pragma unroll
    for (int qq = 0; qq < 2; ++qq) {
      const int chunk = wave * 2 + qq;
      const int row = chunk * 16 + lr;
      load_lds16(&Wt[(rowB0 + row) * 512 + k0 + lc], &sB[chunk * 512]);
      const f32x4 a0 = *(const f32x4*)&A[(rowA0 + row) * 512 + k0 + lc];
      const f32x4 a1 = *(const f32x4*)&A[(rowA0 + row) * 512 + k0 + lc + 4];
      u32x4 pk;
      pk[0] = packrnd(a0[0], a0[1]);
      pk[1] = packrnd(a0[2], a0[3]);
      pk[2] = packrnd(a1[0], a1[1]);
      pk[3] = packrnd(a1[2], a1[3]);
      *(u32x4*)&sA[row * 40 + lc] = pk;
    }
    __syncthreads();
    bf16x8 af[4], bfr[4];
#pragma unroll
    for (int mt = 0; mt < 4; ++mt)
      af[mt] = __builtin_bit_cast(bf16x8, *(const u16x8*)&sA[(wm + mt * 16 + c) * 40 + q * 8]);
#pragma unroll
    for (int nt = 0; nt < 4; ++nt)
      bfr[nt] = __builtin_bit_cast(bf16x8, *(const u16x8*)&sB[(wn + nt * 16 + c) * 32 + q * 8]);
#pragma unroll
    for (int mt = 0; mt < 4; ++mt)
#pragma unroll
      for (int nt = 0; nt < 4; ++nt)
        acc[mt][nt] = mfma16(af[mt], bfr[nt], acc[mt][nt]);
    __syncthreads();
  }

#pragma unroll
  for (int nt = 0; nt < 4; ++nt) {
    const int col = bn * 128 + wn + nt * 16 + c;
    const float bcol = bias[col];
#pragma unroll
    for (int mt = 0; mt < 4; ++mt) {
      const int row0 = bm * 128 + wm + mt * 16 + q * 4;
#pragma unroll
      for (int r = 0; r < 4; ++r) {
        const int row = row0 + r;
        const float v = (acc[mt][nt][r] + bcol) * scale;
        if (MODE == 2) {
          outb[((row >> 10) << 19) + (col << 10) + (row & 1023)] = f2bf(v);
        } else {
          outb[row * 512 + col] = f2bf(v);
        }
      }
    }
  }
}

__global__ __launch_bounds__(256) void k_gemm_qkv(
    const float* __restrict__ tok, const float* __restrict__ pat,
    const unsigned short* __restrict__ WT,
    const float* __restrict__ bq, const float* __restrict__ bk,
    const float* __restrict__ bv,
    unsigned short* __restrict__ QB, unsigned short* __restrict__ KB,
    unsigned short* __restrict__ VTB) {
  __shared__ unsigned short sA[128 * 40];
  __shared__ unsigned short sB[128 * 32];
  const int bid = blockIdx.x;
  if (bid < 512) {
    // scale = 0.125 * log2(e): scores come out in log2 domain for exp2
    gemm_fp32_body<0>(tok, WT, bq, QB, bid, sA, sB, 0.18033688011112042f);
  } else if (bid < 640) {
    gemm_fp32_body<1>(pat, WT + 262144, bk, KB, bid - 512, sA, sB, 1.0f);
  } else {
    gemm_fp32_body<2>(pat, WT + 524288, bv, VTB, bid - 640, sA, sB, 1.0f);
  }
}

// ---------------------------------------------------------------------------
// Out-projection GEMM (bf16 A via DMA): out = CTX @ Wo + bo + resid (fp32).
// ---------------------------------------------------------------------------
__global__ __launch_bounds__(256) void k_gemm_o(
    const unsigned short* __restrict__ A, const unsigned short* __restrict__ Wt,
    const float* __restrict__ bias, float* __restrict__ outf,
    const float* __restrict__ resid) {
  __shared__ unsigned short sA[128 * 32];
  __shared__ unsigned short sB[128 * 32];
  const int tid = threadIdx.x;
  const int wave = tid >> 6, lane = tid & 63;
  const int q = lane >> 4, c = lane & 15;
  const int bm = blockIdx.x >> 2, bn = blockIdx.x & 3;
  const int wm = (wave >> 1) * 64, wn = (wave & 1) * 64;
  const int lr = lane >> 2, lc = (lane & 3) * 8;

  f32x4 acc[4][4];
#pragma unroll
  for (int i = 0; i < 4; ++i)
#pragma unroll
    for (int j = 0; j < 4; ++j) acc[i][j] = (f32x4){0.f, 0.f, 0.f, 0.f};

  const int rowA0 = bm * 128, rowB0 = bn * 128;

  for (int k0 = 0; k0 < 512; k0 += 32) {
#pragma unroll
    for (int qq = 0; qq < 2; ++qq) {
      const int chunk = wave * 2 + qq;
      load_lds16(&A[(rowA0 + chunk * 16 + lr) * 512 + k0 + lc], &sA[chunk * 512]);
      load_lds16(&Wt[(rowB0 + chunk * 16 + lr) * 512 + k0 + lc], &sB[chunk * 512]);
    }
    __syncthreads();
    bf16x8 af[4], bfr[4];
#pragma unroll
    for (int mt = 0; mt < 4; ++mt)
      af[mt] = __builtin_bit_cast(bf16x8, *(const u16x8*)&sA[(wm + mt * 16 + c) * 32 + q * 8]);
#pragma unroll
    for (int nt = 0; nt < 4; ++nt)
      bfr[nt] = __builtin_bit_cast(bf16x8, *(const u16x8*)&sB[(wn + nt * 16 + c) * 32 + q * 8]);
#pragma unroll
    for (int mt = 0; mt < 4; ++mt)
#pragma unroll
      for (int nt = 0; nt < 4; ++nt)
        acc[mt][nt] = mfma16(af[mt], bfr[nt], acc[mt][nt]);
    __syncthreads();
  }

#pragma unroll
  for (int nt = 0; nt < 4; ++nt) {
    const int col = bn * 128 + wn + nt * 16 + c;
    const float bcol = bias[col];
#pragma unroll
    for (int mt = 0; mt < 4; ++mt) {
      const int row0 = bm * 128 + wm + mt * 16 + q * 4;
#pragma unroll
      for (int r = 0; r < 4; ++r) {
        const int row = row0 + r;
        const int o = row * 512 + col;
        outf[o] = acc[mt][nt][r] + bcol + resid[o];
      }
    }
  }
}

// ---------------------------------------------------------------------------
// Kernel 3: block-causal cross attention, no-max softmax in log2 domain.
// 1024 blocks, block = one (tg, b, h) unit (128 tokens), ntile = tg+1.
// Mapping g=bid>>5, tg = g<16 ? g : 47-g makes every stride-256 set
// {j, j+256, j+512, j+768} sum to exactly 66 tiles per CU (uniform), while
// 4 blocks/CU = 16 waves/CU doubles latency hiding vs the round-5 pairing.
// ---------------------------------------------------------------------------
__global__ __launch_bounds__(256) void k_attn(
    const unsigned short* __restrict__ Q,   // [B*T][512], scaled by .125*log2e
    const unsigned short* __restrict__ K,   // [B*P][512]
    const unsigned short* __restrict__ VT,  // [B][512][1024]
    unsigned short* __restrict__ CTX) {     // [B*T][512]
  __shared__ unsigned short sK[2][32 * 88];
  __shared__ unsigned short sV[2][64 * 40];
  __shared__ unsigned short sPT[4][32 * 40];

  const int tid = threadIdx.x;
  const int lane = tid & 63;
  const int wave = tid >> 6;
  const int q = lane >> 4, c = lane & 15;

  const int g = blockIdx.x >> 5;               // [0,32)
  const int tg = (g < 16) ? g : 47 - g;        // uniform-per-CU mapping
  const int bh = blockIdx.x & 31;
  const int b = bh >> 3, h = bh & 7;
  const int t0 = tg * 128 + wave * 32;
  const int tA = t0 + c, tB = t0 + 16 + c;

  const int qbA = (b * TT + tA) * 512 + h * 64 + q * 8;
  const int qbB = (b * TT + tB) * 512 + h * 64 + q * 8;
  const bf16x8 qfA0 = __builtin_bit_cast(bf16x8, *(const u16x8*)&Q[qbA]);
  const bf16x8 qfA1 = __builtin_bit_cast(bf16x8, *(const u16x8*)&Q[qbA + 32]);
  const bf16x8 qfB0 = __builtin_bit_cast(bf16x8, *(const u16x8*)&Q[qbB]);
  const bf16x8 qfB1 = __builtin_bit_cast(bf16x8, *(const u16x8*)&Q[qbB + 32]);

  f32x4 oA[4], oB[4];
#pragma unroll
  for (int m = 0; m < 4; ++m) {
    oA[m] = (f32x4){0.f, 0.f, 0.f, 0.f};
    oB[m] = (f32x4){0.f, 0.f, 0.f, 0.f};
  }
  f32x4 lA = (f32x4){0.f, 0.f, 0.f, 0.f};
  f32x4 lB = lA;
  const u16x8 onesu = {0x3F80, 0x3F80, 0x3F80, 0x3F80, 0x3F80, 0x3F80, 0x3F80, 0x3F80};
  const bf16x8 ones = __builtin_bit_cast(bf16x8, onesu);

  const int ntile = tg + 1;
  const int krow = tid >> 3, kcol = (tid & 7) * 8;
  const int vrow = tid >> 2, vcol = (tid & 3) * 8;
  const int kg = (b * PP + krow) * 512 + h * 64 + kcol;
  const int vg = (b << 19) + ((h * 64 + vrow) << 10) + vcol;
  unsigned short* sp = sPT[wave];

  // stage tile 0
  u16x8 kreg = *(const u16x8*)&K[kg];
  u16x8 vreg = *(const u16x8*)&VT[vg];
  *(u16x8*)&sK[0][krow * 88 + kcol] = kreg;
  *(u16x8*)&sV[0][vrow * 40 + vcol] = vreg;
  __syncthreads();

#pragma unroll 1
  for (int pt = 0; pt < ntile; ++pt) {
    const int buf = pt & 1;
    const bool more = (pt + 1 < ntile);
    if (more) {  // prefetch next tile (overlaps this tile's compute)
      kreg = *(const u16x8*)&K[kg + (pt + 1) * 32 * 512];
      vreg = *(const u16x8*)&VT[vg + (pt + 1) * 32];
    }
    const unsigned short* bK = sK[buf];
    const unsigned short* bV = sV[buf];

    const bf16x8 ka0 = __builtin_bit_cast(bf16x8, *(const u16x8*)&bK[c * 88 + q * 8]);
    const bf16x8 ka1 = __builtin_bit_cast(bf16x8, *(const u16x8*)&bK[c * 88 + 32 + q * 8]);
    const bf16x8 kb0 = __builtin_bit_cast(bf16x8, *(const u16x8*)&bK[(16 + c) * 88 + q * 8]);
    const bf16x8 kb1 = __builtin_bit_cast(bf16x8, *(const u16x8*)&bK[(16 + c) * 88 + 32 + q * 8]);

    const f32x4 z = (f32x4){0.f, 0.f, 0.f, 0.f};
    f32x4 sA0 = mfma16(ka1, qfA1, mfma16(ka0, qfA0, z));  // patches p0+q*4+r
    f32x4 sA1 = mfma16(kb1, qfA1, mfma16(kb0, qfA0, z));  // patches p0+16+q*4+r
    f32x4 sB0 = mfma16(ka1, qfB1, mfma16(ka0, qfB0, z));
    f32x4 sB1 = mfma16(kb1, qfB1, mfma16(kb0, qfB0, z));

    if (pt + 1 == ntile) {  // only the last tile crosses the causal boundary
      const int p0 = pt * 32;
      const int limA = tA >> 2, limB = tB >> 2;
      const int pb0 = p0 + q * 4, pb1 = p0 + 16 + q * 4;
#pragma unroll
      for (int r = 0; r < 4; ++r) {
        if (pb0 + r > limA) sA0[r] = -1e30f;
        if (pb1 + r > limA) sA1[r] = -1e30f;
        if (pb0 + r > limB) sB0[r] = -1e30f;
        if (pb1 + r > limB) sB1[r] = -1e30f;
      }
    }

    float pA0[4], pA1[4], pB0[4], pB1[4];
#pragma unroll
    for (int r = 0; r < 4; ++r) {
      pA0[r] = fexp2(sA0[r]);
      pA1[r] = fexp2(sA1[r]);
      pB0[r] = fexp2(sB0[r]);
      pB1[r] = fexp2(sB1[r]);
    }

    // P -> per-wave LDS [token][patch], stride 40 (truncating pack)
    {
      u32x2 w;
      w[0] = packtr(pA0[0], pA0[1]); w[1] = packtr(pA0[2], pA0[3]);
      *(u32x2*)&sp[c * 40 + q * 4] = w;
      w[0] = packtr(pA1[0], pA1[1]); w[1] = packtr(pA1[2], pA1[3]);
      *(u32x2*)&sp[c * 40 + 16 + q * 4] = w;
      w[0] = packtr(pB0[0], pB0[1]); w[1] = packtr(pB0[2], pB0[3]);
      *(u32x2*)&sp[(16 + c) * 40 + q * 4] = w;
      w[0] = packtr(pB1[0], pB1[1]); w[1] = packtr(pB1[2], pB1[3]);
      *(u32x2*)&sp[(16 + c) * 40 + 16 + q * 4] = w;
    }
    const bf16x8 pbA = __builtin_bit_cast(bf16x8, *(const u16x8*)&sp[c * 40 + q * 8]);
    const bf16x8 pbB = __builtin_bit_cast(bf16x8, *(const u16x8*)&sp[(16 + c) * 40 + q * 8]);

    // ctx^T += V^T . P^T ; l += ones . P^T
#pragma unroll
    for (int mt = 0; mt < 4; ++mt) {
      const bf16x8 vf =
          __builtin_bit_cast(bf16x8, *(const u16x8*)&bV[(mt * 16 + c) * 40 + q * 8]);
      oA[mt] = mfma16(vf, pbA, oA[mt]);
      oB[mt] = mfma16(vf, pbB, oB[mt]);
    }
    lA = mfma16(ones, pbA, lA);
    lB = mfma16(ones, pbB, lB);

    if (more) {  // write next tile into the other buffer, single barrier
      *(u16x8*)&sK[buf ^ 1][krow * 88 + kcol] = kreg;
      *(u16x8*)&sV[buf ^ 1][vrow * 40 + vcol] = vreg;
      __syncthreads();
    }
  }

  const float invA = 1.f / lA[0];
  const float invB = 1.f / lB[0];
  const int obA = (b * TT + tA) * 512 + h * 64 + q * 4;
  const int obB = (b * TT + tB) * 512 + h * 64 + q * 4;
#pragma unroll
  for (int mt = 0; mt < 4; ++mt) {
    u16x4 oa, ob;
#pragma unroll
    for (int r = 0; r < 4; ++r) {
      oa[r] = f2bf(oA[mt][r] * invA);
      ob[r] = f2bf(oB[mt][r] * invB);
    }
    *(u16x4*)&CTX[obA + mt * 16] = oa;
    *(u16x4*)&CTX[obB + mt * 16] = ob;
  }
}

// ---------------------------------------------------------------------------
extern "C" void kernel_launch(void* const* d_in, const int* in_sizes, int n_in,
                              void* d_out, int out_size, void* d_ws, size_t ws_size,
                              hipStream_t stream) {
  const float* tok = (const float*)d_in[0];
  const float* pat = (const float*)d_in[1];
  const float* Wq = (const float*)d_in[2];
  const float* Wk = (const float*)d_in[3];
  const float* Wv = (const float*)d_in[4];
  const float* bq = (const float*)d_in[5];
  const float* bk = (const float*)d_in[6];
  const float* bv = (const float*)d_in[7];
  const float* Wo = (const float*)d_in[8];
  const float* bo = (const float*)d_in[9];
  float* out = (float*)d_out;

  unsigned short* ws = (unsigned short*)d_ws;
  unsigned short* WT = ws;                  // 4 x 512 x 512
  unsigned short* QB = ws + 2097152;        // 16384 x 512
  unsigned short* KB = ws + 10485760;       // 4096 x 512
  unsigned short* VTB = ws + 12582912;      // [4][512][1024]
  unsigned short* CTX = ws + 14680064;      // 16384 x 512   (ends 44 MB)

  k_wconv<<<1024, 256, 0, stream>>>(Wq, Wk, Wv, Wo, WT);
  k_gemm_qkv<<<768, 256, 0, stream>>>(tok, pat, WT, bq, bk, bv, QB, KB, VTB);
  k_attn<<<1024, 256, 0, stream>>>(QB, KB, VTB, CTX);
  k_gemm_o<<<512, 256, 0, stream>>>(CTX, WT + 786432, bo, out, tok);
}